// Round 1
// baseline (2802.548 us; speedup 1.0000x reference)
//
#include <hip/hip_runtime.h>
#include <hip/hip_bf16.h>
#include <math.h>

#define NN  16384      // nodes
#define NE  262144     // edges
#define NG  64         // graphs
#define CIN 16         // input colors
#define DD  256        // embedding
#define NHD 8          // heads
#define DHD 32         // head dim
#define DFF 1024       // ffn dim
#define NLY 4          // layers
#define LM  320        // L_max
#define NR  (LM*NG)    // padded rows = 20480

// ---------------------------------------------------------------- utilities
__global__ void zero_int_kernel(int* __restrict__ p, int n) {
    int i = blockIdx.x * 256 + threadIdx.x;
    if (i < n) p[i] = 0;
}

__global__ void zero_f4_kernel(float4* __restrict__ p, int n4) {
    int i = blockIdx.x * 256 + threadIdx.x;
    if (i < n4) p[i] = make_float4(0.f, 0.f, 0.f, 0.f);
}

// ---------------------------------------------------------------- CSR build
__global__ void count_edges_kernel(const int* __restrict__ dst, int* __restrict__ counts) {
    int e = blockIdx.x * 256 + threadIdx.x;
    if (e < NE) atomicAdd(&counts[dst[e]], 1);
}

__global__ __launch_bounds__(256) void scan_kernel(const int* __restrict__ counts,
                                                   int* __restrict__ offsets,
                                                   int* __restrict__ cursor) {
    __shared__ int part[256];
    int t = threadIdx.x;
    int base = t * 64;            // 256 threads x 64 = 16384
    int s = 0;
    for (int i = 0; i < 64; ++i) s += counts[base + i];
    part[t] = s;
    __syncthreads();
    for (int off = 1; off < 256; off <<= 1) {
        int val = (t >= off) ? part[t - off] : 0;
        __syncthreads();
        part[t] += val;
        __syncthreads();
    }
    int run = (t == 0) ? 0 : part[t - 1];
    for (int i = 0; i < 64; ++i) {
        offsets[base + i] = run;
        cursor[base + i]  = run;
        run += counts[base + i];
    }
    if (t == 255) offsets[NN] = run;
}

__global__ void fill_csr_kernel(const int* __restrict__ src, const int* __restrict__ dst,
                                int* __restrict__ cursor, int* __restrict__ csr) {
    int e = blockIdx.x * 256 + threadIdx.x;
    if (e < NE) {
        int p = atomicAdd(&cursor[dst[e]], 1);
        csr[p] = src[e];
    }
}

// ---------------------------------------------------------------- mean aggregation
__global__ __launch_bounds__(256) void agg_mean16_kernel(
    const float* __restrict__ h, const int* __restrict__ offsets,
    const int* __restrict__ csr, float* __restrict__ out)
{
    int node = blockIdx.x * 16 + (threadIdx.x >> 4);   // 16 nodes / block (16 lanes each)
    int d = threadIdx.x & 15;
    int beg = offsets[node], end = offsets[node + 1];
    float acc = 0.f;
    for (int e = beg; e < end; ++e) {
        int s = csr[e];
        acc += h[(size_t)s * CIN + d];
    }
    int dg = end - beg; if (dg < 1) dg = 1;
    out[(size_t)node * CIN + d] = acc * (1.f / (float)dg);
}

__global__ __launch_bounds__(256) void agg_mean256_kernel(
    const float* __restrict__ h, const int* __restrict__ offsets,
    const int* __restrict__ csr, float* __restrict__ out)
{
    int node = blockIdx.x * 4 + (threadIdx.x >> 6);    // wave per node
    int lane = threadIdx.x & 63;
    int beg = offsets[node], end = offsets[node + 1];
    float4 acc = make_float4(0.f, 0.f, 0.f, 0.f);
    for (int e = beg; e < end; ++e) {
        int s = csr[e];
        const float4 hv = *(const float4*)(h + (size_t)s * DD + lane * 4);
        acc.x += hv.x; acc.y += hv.y; acc.z += hv.z; acc.w += hv.w;
    }
    int dg = end - beg; if (dg < 1) dg = 1;
    float inv = 1.f / (float)dg;
    acc.x *= inv; acc.y *= inv; acc.z *= inv; acc.w *= inv;
    *(float4*)(out + (size_t)node * DD + lane * 4) = acc;
}

// ---------------------------------------------------------------- generic tiled GEMM
// C[M,N] = act( A@W (+ A2@W2) + bias ), A:[M,K] rm, W:[K,N] rm. 64x64 tile, BK=16.
template <int ACT, bool DUAL>
__global__ __launch_bounds__(256) void gemm_kernel(
    const float* __restrict__ A, const float* __restrict__ W,
    const float* __restrict__ A2, const float* __restrict__ W2,
    const float* __restrict__ bias, float* __restrict__ C,
    int M, int N, int K)
{
    __shared__ __align__(16) float As[16][64];
    __shared__ __align__(16) float Ws[16][64];
    const int t  = threadIdx.x;
    const int tx = t & 15, ty = t >> 4;
    const int m0 = blockIdx.y * 64, n0 = blockIdx.x * 64;
    const int arow = t >> 2, acol = (t & 3) * 4;   // A-tile: 64 rows x 16 cols
    const int wrow = t >> 4, wcol = (t & 15) * 4;  // W-tile: 16 rows x 64 cols
    float acc[4][4] = {};
    const int npass = DUAL ? 2 : 1;
    for (int pass = 0; pass < npass; ++pass) {
        const float* Ap = (DUAL && pass) ? A2 : A;
        const float* Wp = (DUAL && pass) ? W2 : W;
        for (int k0 = 0; k0 < K; k0 += 16) {
            __syncthreads();
            float4 av = *(const float4*)(Ap + (size_t)(m0 + arow) * K + k0 + acol);
            As[acol + 0][arow] = av.x;
            As[acol + 1][arow] = av.y;
            As[acol + 2][arow] = av.z;
            As[acol + 3][arow] = av.w;
            *(float4*)&Ws[wrow][wcol] = *(const float4*)(Wp + (size_t)(k0 + wrow) * N + n0 + wcol);
            __syncthreads();
            #pragma unroll
            for (int kk = 0; kk < 16; ++kk) {
                float4 a4 = *(const float4*)&As[kk][ty * 4];
                float4 b4 = *(const float4*)&Ws[kk][tx * 4];
                float aa[4] = {a4.x, a4.y, a4.z, a4.w};
                float bb[4] = {b4.x, b4.y, b4.z, b4.w};
                #pragma unroll
                for (int i = 0; i < 4; ++i)
                    #pragma unroll
                    for (int j = 0; j < 4; ++j)
                        acc[i][j] += aa[i] * bb[j];
            }
        }
    }
    float4 bv = *(const float4*)(bias + n0 + tx * 4);
    float bb4[4] = {bv.x, bv.y, bv.z, bv.w};
    #pragma unroll
    for (int i = 0; i < 4; ++i) {
        float4 cv;
        cv.x = acc[i][0] + bb4[0];
        cv.y = acc[i][1] + bb4[1];
        cv.z = acc[i][2] + bb4[2];
        cv.w = acc[i][3] + bb4[3];
        if (ACT == 1) {
            cv.x = fmaxf(cv.x, 0.f); cv.y = fmaxf(cv.y, 0.f);
            cv.z = fmaxf(cv.z, 0.f); cv.w = fmaxf(cv.w, 0.f);
        }
        *(float4*)(C + (size_t)(m0 + ty * 4 + i) * N + n0 + tx * 4) = cv;
    }
}

// ---------------------------------------------------------------- pack to padded [L,B,D]
__global__ __launch_bounds__(256) void pack_kernel(
    const float* __restrict__ z, const int* __restrict__ batches, float* __restrict__ H)
{
    int node = blockIdx.x * 4 + (threadIdx.x >> 6);
    int lane = threadIdx.x & 63;
    int lo = 0, hi = NG;                 // largest g with batches[g] <= node
    while (lo < hi) {
        int mid = (lo + hi + 1) >> 1;
        if (batches[mid] <= node) lo = mid; else hi = mid - 1;
    }
    int pos = node - batches[lo];
    *(float4*)(H + ((size_t)pos * NG + lo) * DD + lane * 4) =
        *(const float4*)(z + (size_t)node * DD + lane * 4);
}

// ---------------------------------------------------------------- attention (per graph, head)
// q,k,v,o layout: [L, B, H*dh] rows. Only keys m < len participate (pad mask ≡ skip).
#define KT 160
__global__ __launch_bounds__(320) void attn_kernel(
    const float* __restrict__ q, const float* __restrict__ k, const float* __restrict__ v,
    const int* __restrict__ batches, float* __restrict__ o)
{
    __shared__ __align__(16) float Ks[KT][DHD];
    __shared__ __align__(16) float Vs[KT][DHD];
    const int b  = blockIdx.x >> 3;
    const int hd = blockIdx.x & 7;
    const int len = batches[b + 1] - batches[b];
    const int t = threadIdx.x;           // == q row r, 0..319 (all rows incl. padded)
    const size_t rowbase = ((size_t)t * NG + b) * DD + hd * DHD;

    float qr[DHD];
    {
        const float4* q4 = (const float4*)(q + rowbase);
        #pragma unroll
        for (int i = 0; i < 8; ++i) {
            float4 t4 = q4[i];
            qr[4*i+0] = t4.x * 0.17677669529663687f;   // 1/sqrt(32)
            qr[4*i+1] = t4.y * 0.17677669529663687f;
            qr[4*i+2] = t4.z * 0.17677669529663687f;
            qr[4*i+3] = t4.w * 0.17677669529663687f;
        }
    }
    float mrun = -1e30f, lrun = 0.f;
    float acc[DHD];
    #pragma unroll
    for (int d = 0; d < DHD; ++d) acc[d] = 0.f;

    for (int t0 = 0; t0 < len; t0 += KT) {
        const int tl = (len - t0 < KT) ? (len - t0) : KT;
        __syncthreads();
        for (int idx = t; idx < tl * DHD; idx += 320) {
            int m = idx >> 5, d = idx & 31;
            size_t gb = ((size_t)(t0 + m) * NG + b) * DD + hd * DHD + d;
            Ks[m][d] = k[gb];
            Vs[m][d] = v[gb];
        }
        __syncthreads();
        for (int m = 0; m < tl; ++m) {
            const float4* kr = (const float4*)Ks[m];
            float s = 0.f;
            #pragma unroll
            for (int i = 0; i < 8; ++i) {
                float4 kv = kr[i];
                s += qr[4*i+0]*kv.x + qr[4*i+1]*kv.y + qr[4*i+2]*kv.z + qr[4*i+3]*kv.w;
            }
            if (s > mrun) {
                float f = __expf(mrun - s);
                lrun *= f;
                #pragma unroll
                for (int d2 = 0; d2 < DHD; ++d2) acc[d2] *= f;
                mrun = s;
            }
            float pexp = __expf(s - mrun);
            lrun += pexp;
            const float4* vr = (const float4*)Vs[m];
            #pragma unroll
            for (int i = 0; i < 8; ++i) {
                float4 vv = vr[i];
                acc[4*i+0] += pexp * vv.x;
                acc[4*i+1] += pexp * vv.y;
                acc[4*i+2] += pexp * vv.z;
                acc[4*i+3] += pexp * vv.w;
            }
        }
    }
    float inv = 1.f / lrun;
    float4* o4 = (float4*)(o + rowbase);
    #pragma unroll
    for (int i = 0; i < 8; ++i) {
        float4 ov;
        ov.x = acc[4*i+0] * inv;
        ov.y = acc[4*i+1] * inv;
        ov.z = acc[4*i+2] * inv;
        ov.w = acc[4*i+3] * inv;
        o4[i] = ov;
    }
}

// ---------------------------------------------------------------- residual + LayerNorm
__global__ __launch_bounds__(256) void add_ln_kernel(
    const float* __restrict__ x, const float* __restrict__ r,
    const float* __restrict__ g, const float* __restrict__ bb,
    float* __restrict__ out)
{
    int row  = blockIdx.x * 4 + (threadIdx.x >> 6);
    int lane = threadIdx.x & 63;
    size_t base = (size_t)row * DD + lane * 4;
    float4 xv = *(const float4*)(x + base);
    float4 rv = *(const float4*)(r + base);
    float t0 = xv.x + rv.x, t1 = xv.y + rv.y, t2 = xv.z + rv.z, t3 = xv.w + rv.w;
    float s1 = t0 + t1 + t2 + t3;
    float s2 = t0*t0 + t1*t1 + t2*t2 + t3*t3;
    #pragma unroll
    for (int off = 32; off > 0; off >>= 1) {
        s1 += __shfl_xor(s1, off, 64);
        s2 += __shfl_xor(s2, off, 64);
    }
    float mean = s1 * (1.f / 256.f);
    float var  = s2 * (1.f / 256.f) - mean * mean;
    float rs = rsqrtf(var + 1e-5f);
    float4 gv = *(const float4*)(g + lane * 4);
    float4 bv = *(const float4*)(bb + lane * 4);
    float4 ov;
    ov.x = (t0 - mean) * rs * gv.x + bv.x;
    ov.y = (t1 - mean) * rs * gv.y + bv.y;
    ov.z = (t2 - mean) * rs * gv.z + bv.z;
    ov.w = (t3 - mean) * rs * gv.w + bv.w;
    *(float4*)(out + base) = ov;
}

// ---------------------------------------------------------------- launcher
extern "C" void kernel_launch(void* const* d_in, const int* in_sizes, int n_in,
                              void* d_out, int out_size, void* d_ws, size_t ws_size,
                              hipStream_t stream) {
    const float* x       = (const float*)d_in[0];
    const int*   ei      = (const int*)d_in[1];   // [2, NE]: row0 src, row1 dst
    const int*   batches = (const int*)d_in[2];   // [NG+1]
    // d_in[3] = L_max scalar (known constant 320)
    const float* sW0  = (const float*)d_in[4];
    const float* sWn0 = (const float*)d_in[5];
    const float* sb0  = (const float*)d_in[6];
    const float* sW1  = (const float*)d_in[7];
    const float* sWn1 = (const float*)d_in[8];
    const float* sb1  = (const float*)d_in[9];
    const float* sW2  = (const float*)d_in[10];
    const float* sWn2 = (const float*)d_in[11];
    const float* sb2  = (const float*)d_in[12];
    const float* Wq   = (const float*)d_in[13];
    const float* Wk   = (const float*)d_in[14];
    const float* Wv   = (const float*)d_in[15];
    const float* bq   = (const float*)d_in[16];
    const float* bk   = (const float*)d_in[17];
    const float* bv   = (const float*)d_in[18];
    const float* Wo   = (const float*)d_in[19];
    const float* bo   = (const float*)d_in[20];
    const float* ln1g = (const float*)d_in[21];
    const float* ln1b = (const float*)d_in[22];
    const float* ln2g = (const float*)d_in[23];
    const float* ln2b = (const float*)d_in[24];
    const float* W1   = (const float*)d_in[25];
    const float* b1   = (const float*)d_in[26];
    const float* W2   = (const float*)d_in[27];
    const float* b2   = (const float*)d_in[28];

    char* p = (char*)d_ws;
    auto alloc = [&](size_t bytes) {
        char* r = p;
        p += (bytes + 255) & ~(size_t)255;
        return r;
    };
    int*   counts  = (int*)alloc((size_t)NN * 4);
    int*   offsets = (int*)alloc((size_t)(NN + 1) * 4);
    int*   cursor  = (int*)alloc((size_t)NN * 4);
    int*   csr     = (int*)alloc((size_t)NE * 4);
    float* bufA    = (float*)alloc((size_t)NN * DD * 4);
    float* bufB    = (float*)alloc((size_t)NN * DD * 4);
    float* bufC    = (float*)alloc((size_t)NN * DD * 4);
    float* H       = (float*)alloc((size_t)NR * DD * 4);
    float* Q       = (float*)alloc((size_t)NR * DD * 4);   // Q..O contiguous:
    float* Kb      = (float*)alloc((size_t)NR * DD * 4);   //   F1 [NR,1024] aliases
    float* Vb      = (float*)alloc((size_t)NR * DD * 4);   //   the 4-buffer span
    float* O       = (float*)alloc((size_t)NR * DD * 4);
    float* F1      = Q;
    float* F2      = (float*)alloc((size_t)NR * DD * 4);

    // ---- CSR build (every call: ws is re-poisoned) ----
    zero_int_kernel<<<NN / 256, 256, 0, stream>>>(counts, NN);
    count_edges_kernel<<<NE / 256, 256, 0, stream>>>(ei + NE, counts);
    scan_kernel<<<1, 256, 0, stream>>>(counts, offsets, cursor);
    fill_csr_kernel<<<NE / 256, 256, 0, stream>>>(ei, ei + NE, cursor, csr);

    // ---- SAGE layers ----
    agg_mean16_kernel<<<NN / 16, 256, 0, stream>>>(x, offsets, csr, bufB);
    gemm_kernel<1, true><<<dim3(DD / 64, NN / 64), 256, 0, stream>>>(
        x, sW0, bufB, sWn0, sb0, bufA, NN, DD, CIN);
    agg_mean256_kernel<<<NN / 4, 256, 0, stream>>>(bufA, offsets, csr, bufB);
    gemm_kernel<1, true><<<dim3(DD / 64, NN / 64), 256, 0, stream>>>(
        bufA, sW1, bufB, sWn1, sb1, bufC, NN, DD, DD);
    agg_mean256_kernel<<<NN / 4, 256, 0, stream>>>(bufC, offsets, csr, bufB);
    gemm_kernel<0, true><<<dim3(DD / 64, NN / 64), 256, 0, stream>>>(
        bufC, sW2, bufB, sWn2, sb2, bufA, NN, DD, DD);

    // ---- pack to padded [L, B, D] ----
    zero_f4_kernel<<<(NR * DD / 4) / 256, 256, 0, stream>>>((float4*)H, NR * DD / 4);
    pack_kernel<<<NN / 4, 256, 0, stream>>>(bufA, batches, H);

    // ---- transformer layers ----
    for (int l = 0; l < NLY; ++l) {
        const size_t wo = (size_t)l * DD * DD;
        gemm_kernel<0, false><<<dim3(DD / 64, NR / 64), 256, 0, stream>>>(
            H, Wq + wo, nullptr, nullptr, bq + l * DD, Q, NR, DD, DD);
        gemm_kernel<0, false><<<dim3(DD / 64, NR / 64), 256, 0, stream>>>(
            H, Wk + wo, nullptr, nullptr, bk + l * DD, Kb, NR, DD, DD);
        gemm_kernel<0, false><<<dim3(DD / 64, NR / 64), 256, 0, stream>>>(
            H, Wv + wo, nullptr, nullptr, bv + l * DD, Vb, NR, DD, DD);
        attn_kernel<<<NG * NHD, 320, 0, stream>>>(Q, Kb, Vb, batches, O);
        gemm_kernel<0, false><<<dim3(DD / 64, NR / 64), 256, 0, stream>>>(
            O, Wo + wo, nullptr, nullptr, bo + l * DD, Q, NR, DD, DD);   // o2 -> Q
        add_ln_kernel<<<NR / 4, 256, 0, stream>>>(H, Q, ln1g + l * DD, ln1b + l * DD, H);
        gemm_kernel<1, false><<<dim3(DFF / 64, NR / 64), 256, 0, stream>>>(
            H, W1 + (size_t)l * DD * DFF, nullptr, nullptr, b1 + l * DFF, F1, NR, DFF, DD);
        gemm_kernel<0, false><<<dim3(DD / 64, NR / 64), 256, 0, stream>>>(
            F1, W2 + (size_t)l * DFF * DD, nullptr, nullptr, b2 + l * DD, F2, NR, DD, DFF);
        float* outp = (l == NLY - 1) ? (float*)d_out : H;
        add_ln_kernel<<<NR / 4, 256, 0, stream>>>(H, F2, ln2g + l * DD, ln2b + l * DD, outp);
    }
}

// Round 2
// 1373.750 us; speedup vs baseline: 2.0401x; 2.0401x over previous
//
#include <hip/hip_runtime.h>
#include <hip/hip_bf16.h>
#include <math.h>

#define NN  16384      // nodes
#define NE  262144     // edges
#define NG  64         // graphs
#define CIN 16         // input colors
#define DD  256        // embedding
#define NHD 8          // heads
#define DHD 32         // head dim
#define DFF 1024       // ffn dim
#define NLY 4          // layers
#define LM  320        // L_max
#define NR  (LM*NG)    // padded rows = 20480
#define QS  768        // fused QKV row stride

typedef __attribute__((ext_vector_type(8))) short bf16x8;
typedef __attribute__((ext_vector_type(4))) float f32x4;
typedef __attribute__((ext_vector_type(8))) unsigned short u16x8;

__device__ __forceinline__ unsigned short f2bf(float f) {
    union { __hip_bfloat16 h; unsigned short u; } cv;
    cv.h = __float2bfloat16(f);
    return cv.u;
}
__device__ __forceinline__ float bf2f(unsigned short u) {
    return __uint_as_float((unsigned int)u << 16);
}

// ---------------------------------------------------------------- utilities
__global__ void zero_int_kernel(int* __restrict__ p, int n) {
    int i = blockIdx.x * 256 + threadIdx.x;
    if (i < n) p[i] = 0;
}
__global__ void zero_f4_kernel(float4* __restrict__ p, int n4) {
    int i = blockIdx.x * 256 + threadIdx.x;
    if (i < n4) p[i] = make_float4(0.f, 0.f, 0.f, 0.f);
}

// ---------------------------------------------------------------- weight prep (f32 -> bf16, transposed [N][K])
__global__ void prep_t_kernel(const float* __restrict__ in, unsigned short* __restrict__ out,
                              int L, int K, int N) {
    int i = blockIdx.x * 256 + threadIdx.x;
    if (i >= L * K * N) return;
    int k = i % K;
    int n = (i / K) % N;
    int l = i / (K * N);
    out[i] = f2bf(in[((size_t)l * K + k) * N + n]);
}

__global__ void prep_qkv_kernel(const float* __restrict__ Wq, const float* __restrict__ Wk,
                                const float* __restrict__ Wv, unsigned short* __restrict__ out) {
    int i = blockIdx.x * 256 + threadIdx.x;   // [l][n(768)][k(256)]
    if (i >= NLY * QS * DD) return;
    int k = i & 255;
    int n = (i >> 8) % QS;
    int l = i / (QS * DD);
    const float* W = (n < 256) ? Wq : (n < 512 ? Wk : Wv);
    out[i] = f2bf(W[((size_t)l * DD + k) * DD + (n & 255)]);
}

__global__ void prep_bias_kernel(const float* __restrict__ bq, const float* __restrict__ bk,
                                 const float* __restrict__ bv, float* __restrict__ out) {
    int i = blockIdx.x * 256 + threadIdx.x;   // [l][n(768)]
    if (i >= NLY * QS) return;
    int n = i % QS, l = i / QS;
    const float* b = (n < 256) ? bq : (n < 512 ? bk : bv);
    out[i] = b[l * DD + (n & 255)];
}

// ---------------------------------------------------------------- CSR build
__global__ void count_edges_kernel(const int* __restrict__ dst, int* __restrict__ counts) {
    int e = blockIdx.x * 256 + threadIdx.x;
    if (e < NE) atomicAdd(&counts[dst[e]], 1);
}

__global__ __launch_bounds__(256) void scan_kernel(const int* __restrict__ counts,
                                                   int* __restrict__ offsets,
                                                   int* __restrict__ cursor) {
    __shared__ int part[256];
    int t = threadIdx.x;
    int base = t * 64;
    int s = 0;
    for (int i = 0; i < 64; ++i) s += counts[base + i];
    part[t] = s;
    __syncthreads();
    for (int off = 1; off < 256; off <<= 1) {
        int val = (t >= off) ? part[t - off] : 0;
        __syncthreads();
        part[t] += val;
        __syncthreads();
    }
    int run = (t == 0) ? 0 : part[t - 1];
    for (int i = 0; i < 64; ++i) {
        offsets[base + i] = run;
        cursor[base + i]  = run;
        run += counts[base + i];
    }
    if (t == 255) offsets[NN] = run;
}

__global__ void fill_csr_kernel(const int* __restrict__ src, const int* __restrict__ dst,
                                int* __restrict__ cursor, int* __restrict__ csr) {
    int e = blockIdx.x * 256 + threadIdx.x;
    if (e < NE) {
        int p = atomicAdd(&cursor[dst[e]], 1);
        csr[p] = src[e];
    }
}

// ---------------------------------------------------------------- mean aggregation
__global__ __launch_bounds__(256) void agg_mean16_kernel(
    const float* __restrict__ h, const int* __restrict__ offsets,
    const int* __restrict__ csr, float* __restrict__ out)
{
    int node = blockIdx.x * 16 + (threadIdx.x >> 4);
    int d = threadIdx.x & 15;
    int beg = offsets[node], end = offsets[node + 1];
    float acc = 0.f;
    for (int e = beg; e < end; ++e) acc += h[(size_t)csr[e] * CIN + d];
    int dg = end - beg; if (dg < 1) dg = 1;
    out[(size_t)node * CIN + d] = acc * (1.f / (float)dg);
}

// bf16 in, bf16 out mean aggregation (f32 accumulate)
__global__ __launch_bounds__(256) void agg_mean_b_kernel(
    const unsigned short* __restrict__ h, const int* __restrict__ offsets,
    const int* __restrict__ csr, unsigned short* __restrict__ out)
{
    int node = blockIdx.x * 4 + (threadIdx.x >> 6);
    int lane = threadIdx.x & 63;
    int beg = offsets[node], end = offsets[node + 1];
    float a0 = 0.f, a1 = 0.f, a2 = 0.f, a3 = 0.f;
    for (int e = beg; e < end; ++e) {
        const ushort4 hv = *(const ushort4*)(h + (size_t)csr[e] * DD + lane * 4);
        a0 += bf2f(hv.x); a1 += bf2f(hv.y); a2 += bf2f(hv.z); a3 += bf2f(hv.w);
    }
    int dg = end - beg; if (dg < 1) dg = 1;
    float inv = 1.f / (float)dg;
    ushort4 ov;
    ov.x = f2bf(a0 * inv); ov.y = f2bf(a1 * inv);
    ov.z = f2bf(a2 * inv); ov.w = f2bf(a3 * inv);
    *(ushort4*)(out + (size_t)node * DD + lane * 4) = ov;
}

// ---------------------------------------------------------------- f32 tiled GEMM (SAGE layer0, K=16) -> bf16 out
template <int ACT, bool DUAL>
__global__ __launch_bounds__(256) void gemm_f32b_kernel(
    const float* __restrict__ A, const float* __restrict__ W,
    const float* __restrict__ A2, const float* __restrict__ W2,
    const float* __restrict__ bias, unsigned short* __restrict__ Cb,
    int M, int N, int K)
{
    __shared__ __align__(16) float As[16][64];
    __shared__ __align__(16) float Ws[16][64];
    const int t  = threadIdx.x;
    const int tx = t & 15, ty = t >> 4;
    const int m0 = blockIdx.y * 64, n0 = blockIdx.x * 64;
    const int arow = t >> 2, acol = (t & 3) * 4;
    const int wrow = t >> 4, wcol = (t & 15) * 4;
    float acc[4][4] = {};
    const int npass = DUAL ? 2 : 1;
    for (int pass = 0; pass < npass; ++pass) {
        const float* Ap = (DUAL && pass) ? A2 : A;
        const float* Wp = (DUAL && pass) ? W2 : W;
        for (int k0 = 0; k0 < K; k0 += 16) {
            __syncthreads();
            float4 av = *(const float4*)(Ap + (size_t)(m0 + arow) * K + k0 + acol);
            As[acol + 0][arow] = av.x;
            As[acol + 1][arow] = av.y;
            As[acol + 2][arow] = av.z;
            As[acol + 3][arow] = av.w;
            *(float4*)&Ws[wrow][wcol] = *(const float4*)(Wp + (size_t)(k0 + wrow) * N + n0 + wcol);
            __syncthreads();
            #pragma unroll
            for (int kk = 0; kk < 16; ++kk) {
                float4 a4 = *(const float4*)&As[kk][ty * 4];
                float4 b4 = *(const float4*)&Ws[kk][tx * 4];
                float aa[4] = {a4.x, a4.y, a4.z, a4.w};
                float bb[4] = {b4.x, b4.y, b4.z, b4.w};
                #pragma unroll
                for (int i = 0; i < 4; ++i)
                    #pragma unroll
                    for (int j = 0; j < 4; ++j)
                        acc[i][j] += aa[i] * bb[j];
            }
        }
    }
    float4 bv = *(const float4*)(bias + n0 + tx * 4);
    float bb4[4] = {bv.x, bv.y, bv.z, bv.w};
    #pragma unroll
    for (int i = 0; i < 4; ++i) {
        float c[4];
        #pragma unroll
        for (int j = 0; j < 4; ++j) {
            c[j] = acc[i][j] + bb4[j];
            if (ACT == 1) c[j] = fmaxf(c[j], 0.f);
        }
        ushort4 ov;
        ov.x = f2bf(c[0]); ov.y = f2bf(c[1]); ov.z = f2bf(c[2]); ov.w = f2bf(c[3]);
        *(ushort4*)(Cb + (size_t)(m0 + ty * 4 + i) * N + n0 + tx * 4) = ov;
    }
}

// ---------------------------------------------------------------- bf16 MFMA GEMM
// C[M,N] = act( A@W (+A2@W2) + bias ); A:[M,K] bf16 rm, Wt:[N,K] bf16 (pre-transposed).
// 128x128 tile, BK=32, 4 waves, each wave 64x64 via 4x4 of 16x16x32 MFMA.
template <int ACT, bool DUAL, bool OUTF32, bool OUTBF16>
__global__ __launch_bounds__(256) void mfma_gemm_kernel(
    const unsigned short* __restrict__ A,  const unsigned short* __restrict__ Wt,
    const unsigned short* __restrict__ A2, const unsigned short* __restrict__ Wt2,
    const float* __restrict__ bias, float* __restrict__ Cf,
    unsigned short* __restrict__ Cb, int M, int N, int K)
{
    __shared__ __align__(16) unsigned short As[128][40];   // +8 pad: row stride 80B
    __shared__ __align__(16) unsigned short Bs[128][40];
    const int t = threadIdx.x;
    const int wave = t >> 6, lane = t & 63;
    const int quad = lane >> 4, r16 = lane & 15;
    const int wr = (wave >> 1) * 64, wc = (wave & 1) * 64;
    const int m0 = blockIdx.y * 128, n0 = blockIdx.x * 128;
    const int srow = t >> 2, sq = (t & 3) * 8;

    f32x4 acc[4][4];
    #pragma unroll
    for (int i = 0; i < 4; ++i)
        #pragma unroll
        for (int j = 0; j < 4; ++j)
            acc[i][j] = (f32x4){0.f, 0.f, 0.f, 0.f};

    const int npass = DUAL ? 2 : 1;
    for (int pass = 0; pass < npass; ++pass) {
        const unsigned short* Ap = (DUAL && pass) ? A2 : A;
        const unsigned short* Wp = (DUAL && pass) ? Wt2 : Wt;
        for (int k0 = 0; k0 < K; k0 += 32) {
            __syncthreads();
            *(uint4*)&As[srow][sq]      = *(const uint4*)&Ap[(size_t)(m0 + srow) * K + k0 + sq];
            *(uint4*)&As[srow + 64][sq] = *(const uint4*)&Ap[(size_t)(m0 + srow + 64) * K + k0 + sq];
            *(uint4*)&Bs[srow][sq]      = *(const uint4*)&Wp[(size_t)(n0 + srow) * K + k0 + sq];
            *(uint4*)&Bs[srow + 64][sq] = *(const uint4*)&Wp[(size_t)(n0 + srow + 64) * K + k0 + sq];
            __syncthreads();
            bf16x8 af[4], bfr[4];
            #pragma unroll
            for (int i = 0; i < 4; ++i)
                af[i] = *(const bf16x8*)&As[wr + i * 16 + r16][quad * 8];
            #pragma unroll
            for (int j = 0; j < 4; ++j)
                bfr[j] = *(const bf16x8*)&Bs[wc + j * 16 + r16][quad * 8];
            #pragma unroll
            for (int i = 0; i < 4; ++i)
                #pragma unroll
                for (int j = 0; j < 4; ++j)
                    acc[i][j] = __builtin_amdgcn_mfma_f32_16x16x32_bf16(
                        af[i], bfr[j], acc[i][j], 0, 0, 0);
        }
    }

    float bcol[4];
    #pragma unroll
    for (int j = 0; j < 4; ++j) bcol[j] = bias[n0 + wc + j * 16 + r16];
    #pragma unroll
    for (int i = 0; i < 4; ++i) {
        const int rowb = m0 + wr + i * 16 + quad * 4;
        #pragma unroll
        for (int rr = 0; rr < 4; ++rr) {
            const size_t rb = (size_t)(rowb + rr) * N;
            #pragma unroll
            for (int j = 0; j < 4; ++j) {
                float v = acc[i][j][rr] + bcol[j];
                if (ACT == 1) v = fmaxf(v, 0.f);
                const int col = n0 + wc + j * 16 + r16;
                if (OUTF32) Cf[rb + col] = v;
                if (OUTBF16) Cb[rb + col] = f2bf(v);
            }
        }
    }
}

// ---------------------------------------------------------------- pack to padded [L,B,D] (f32 + bf16)
__global__ __launch_bounds__(256) void pack_kernel(
    const float* __restrict__ z, const int* __restrict__ batches,
    float* __restrict__ Hf, unsigned short* __restrict__ Hb)
{
    int node = blockIdx.x * 4 + (threadIdx.x >> 6);
    int lane = threadIdx.x & 63;
    int lo = 0, hi = NG;
    while (lo < hi) {
        int mid = (lo + hi + 1) >> 1;
        if (batches[mid] <= node) lo = mid; else hi = mid - 1;
    }
    int pos = node - batches[lo];
    size_t base = ((size_t)pos * NG + lo) * DD + lane * 4;
    float4 zv = *(const float4*)(z + (size_t)node * DD + lane * 4);
    *(float4*)(Hf + base) = zv;
    ushort4 hb;
    hb.x = f2bf(zv.x); hb.y = f2bf(zv.y); hb.z = f2bf(zv.z); hb.w = f2bf(zv.w);
    *(ushort4*)(Hb + base) = hb;
}

// ---------------------------------------------------------------- attention (per graph, head)
// qkv: [L, B, 768] f32 fused rows (Q|K|V). Output: bf16 [L, B, 256].
#define KT 160
__global__ __launch_bounds__(320) void attn_kernel(
    const float* __restrict__ qkv, const int* __restrict__ batches,
    unsigned short* __restrict__ o)
{
    __shared__ __align__(16) float Ks[KT][DHD];
    __shared__ __align__(16) float Vs[KT][DHD];
    const int b  = blockIdx.x >> 3;
    const int hd = blockIdx.x & 7;
    const int len = batches[b + 1] - batches[b];
    const int t = threadIdx.x;           // q row 0..319 (padded rows included)
    const size_t qbase = ((size_t)t * NG + b) * QS + hd * DHD;

    float qr[DHD];
    {
        const float4* q4 = (const float4*)(qkv + qbase);
        #pragma unroll
        for (int i = 0; i < 8; ++i) {
            float4 t4 = q4[i];
            qr[4*i+0] = t4.x * 0.17677669529663687f;   // 1/sqrt(32)
            qr[4*i+1] = t4.y * 0.17677669529663687f;
            qr[4*i+2] = t4.z * 0.17677669529663687f;
            qr[4*i+3] = t4.w * 0.17677669529663687f;
        }
    }
    float mrun = -1e30f, lrun = 0.f;
    float acc[DHD];
    #pragma unroll
    for (int d = 0; d < DHD; ++d) acc[d] = 0.f;

    for (int t0 = 0; t0 < len; t0 += KT) {
        const int tl = (len - t0 < KT) ? (len - t0) : KT;
        __syncthreads();
        for (int idx = t; idx < tl * DHD; idx += 320) {
            int m = idx >> 5, d = idx & 31;
            size_t gb = ((size_t)(t0 + m) * NG + b) * QS + hd * DHD + d;
            Ks[m][d] = qkv[gb + 256];
            Vs[m][d] = qkv[gb + 512];
        }
        __syncthreads();
        for (int m = 0; m < tl; ++m) {
            const float4* kr = (const float4*)Ks[m];
            float s = 0.f;
            #pragma unroll
            for (int i = 0; i < 8; ++i) {
                float4 kv = kr[i];
                s += qr[4*i+0]*kv.x + qr[4*i+1]*kv.y + qr[4*i+2]*kv.z + qr[4*i+3]*kv.w;
            }
            if (s > mrun) {
                float f = __expf(mrun - s);
                lrun *= f;
                #pragma unroll
                for (int d2 = 0; d2 < DHD; ++d2) acc[d2] *= f;
                mrun = s;
            }
            float pexp = __expf(s - mrun);
            lrun += pexp;
            const float4* vr = (const float4*)Vs[m];
            #pragma unroll
            for (int i = 0; i < 8; ++i) {
                float4 vv = vr[i];
                acc[4*i+0] += pexp * vv.x;
                acc[4*i+1] += pexp * vv.y;
                acc[4*i+2] += pexp * vv.z;
                acc[4*i+3] += pexp * vv.w;
            }
        }
    }
    float inv = 1.f / lrun;
    unsigned short* ob = o + ((size_t)t * NG + b) * DD + hd * DHD;
    #pragma unroll
    for (int c = 0; c < 4; ++c) {
        u16x8 pk;
        #pragma unroll
        for (int e = 0; e < 8; ++e) pk[e] = f2bf(acc[c * 8 + e] * inv);
        *((u16x8*)ob + c) = pk;
    }
}

// ---------------------------------------------------------------- residual + LayerNorm (f32 + bf16 out)
__global__ __launch_bounds__(256) void add_ln_kernel(
    const float* __restrict__ x, const float* __restrict__ r,
    const float* __restrict__ g, const float* __restrict__ bb,
    float* __restrict__ outf, unsigned short* __restrict__ outb)
{
    int row  = blockIdx.x * 4 + (threadIdx.x >> 6);
    int lane = threadIdx.x & 63;
    size_t base = (size_t)row * DD + lane * 4;
    float4 xv = *(const float4*)(x + base);
    float4 rv = *(const float4*)(r + base);
    float t0 = xv.x + rv.x, t1 = xv.y + rv.y, t2 = xv.z + rv.z, t3 = xv.w + rv.w;
    float s1 = t0 + t1 + t2 + t3;
    float s2 = t0*t0 + t1*t1 + t2*t2 + t3*t3;
    #pragma unroll
    for (int off = 32; off > 0; off >>= 1) {
        s1 += __shfl_xor(s1, off, 64);
        s2 += __shfl_xor(s2, off, 64);
    }
    float mean = s1 * (1.f / 256.f);
    float var  = s2 * (1.f / 256.f) - mean * mean;
    float rs = rsqrtf(var + 1e-5f);
    float4 gv = *(const float4*)(g + lane * 4);
    float4 bv = *(const float4*)(bb + lane * 4);
    float4 ov;
    ov.x = (t0 - mean) * rs * gv.x + bv.x;
    ov.y = (t1 - mean) * rs * gv.y + bv.y;
    ov.z = (t2 - mean) * rs * gv.z + bv.z;
    ov.w = (t3 - mean) * rs * gv.w + bv.w;
    *(float4*)(outf + base) = ov;
    ushort4 ob;
    ob.x = f2bf(ov.x); ob.y = f2bf(ov.y); ob.z = f2bf(ov.z); ob.w = f2bf(ov.w);
    *(ushort4*)(outb + base) = ob;
}

// ---------------------------------------------------------------- launcher
extern "C" void kernel_launch(void* const* d_in, const int* in_sizes, int n_in,
                              void* d_out, int out_size, void* d_ws, size_t ws_size,
                              hipStream_t stream) {
    const float* x       = (const float*)d_in[0];
    const int*   ei      = (const int*)d_in[1];
    const int*   batches = (const int*)d_in[2];
    const float* sW0  = (const float*)d_in[4];
    const float* sWn0 = (const float*)d_in[5];
    const float* sb0  = (const float*)d_in[6];
    const float* sW1  = (const float*)d_in[7];
    const float* sWn1 = (const float*)d_in[8];
    const float* sb1  = (const float*)d_in[9];
    const float* sW2  = (const float*)d_in[10];
    const float* sWn2 = (const float*)d_in[11];
    const float* sb2  = (const float*)d_in[12];
    const float* Wq   = (const float*)d_in[13];
    const float* Wk   = (const float*)d_in[14];
    const float* Wv   = (const float*)d_in[15];
    const float* bq   = (const float*)d_in[16];
    const float* bk   = (const float*)d_in[17];
    const float* bv   = (const float*)d_in[18];
    const float* Wo   = (const float*)d_in[19];
    const float* bo   = (const float*)d_in[20];
    const float* ln1g = (const float*)d_in[21];
    const float* ln1b = (const float*)d_in[22];
    const float* ln2g = (const float*)d_in[23];
    const float* ln2b = (const float*)d_in[24];
    const float* W1   = (const float*)d_in[25];
    const float* b1   = (const float*)d_in[26];
    const float* W2   = (const float*)d_in[27];
    const float* b2   = (const float*)d_in[28];

    char* p = (char*)d_ws;
    auto alloc = [&](size_t bytes) {
        char* r = p;
        p += (bytes + 255) & ~(size_t)255;
        return r;
    };
    int*   counts  = (int*)alloc((size_t)NN * 4);
    int*   offsets = (int*)alloc((size_t)(NN + 1) * 4);
    int*   cursor  = (int*)alloc((size_t)NN * 4);
    int*   csr     = (int*)alloc((size_t)NE * 4);
    float* agg0    = (float*)alloc((size_t)NN * CIN * 4);
    unsigned short* z0b = (unsigned short*)alloc((size_t)NN * DD * 2);
    unsigned short* a1b = (unsigned short*)alloc((size_t)NN * DD * 2);
    unsigned short* z1b = (unsigned short*)alloc((size_t)NN * DD * 2);
    unsigned short* a2b = (unsigned short*)alloc((size_t)NN * DD * 2);
    float* z2f     = (float*)alloc((size_t)NN * DD * 4);
    float* Hf      = (float*)alloc((size_t)NR * DD * 4);
    unsigned short* Hb = (unsigned short*)alloc((size_t)NR * DD * 2);
    unsigned short* Ob = (unsigned short*)alloc((size_t)NR * DD * 2);
    float* R       = (float*)alloc((size_t)NR * QS * 4);       // QKVf / Of / F1b / F2f alias region
    float* QKVf    = R;
    float* Of      = R;
    unsigned short* F1b = (unsigned short*)R;                  // [NR,1024] bf16 = 40 MB
    float* F2f     = (float*)((char*)R + (size_t)NR * DFF * 2);
    // weights (bf16, transposed [N][K])
    unsigned short* Wqkvt = (unsigned short*)alloc((size_t)NLY * QS * DD * 2);
    unsigned short* Wot   = (unsigned short*)alloc((size_t)NLY * DD * DD * 2);
    unsigned short* W1t   = (unsigned short*)alloc((size_t)NLY * DFF * DD * 2);
    unsigned short* W2t   = (unsigned short*)alloc((size_t)NLY * DD * DFF * 2);
    unsigned short* sW1t  = (unsigned short*)alloc((size_t)DD * DD * 2);
    unsigned short* sWn1t = (unsigned short*)alloc((size_t)DD * DD * 2);
    unsigned short* sW2t  = (unsigned short*)alloc((size_t)DD * DD * 2);
    unsigned short* sWn2t = (unsigned short*)alloc((size_t)DD * DD * 2);
    float* bqkvp   = (float*)alloc((size_t)NLY * QS * 4);

    // ---- weight prep ----
    prep_qkv_kernel<<<(NLY*QS*DD + 255)/256, 256, 0, stream>>>(Wq, Wk, Wv, Wqkvt);
    prep_t_kernel<<<(NLY*DD*DD + 255)/256, 256, 0, stream>>>(Wo, Wot, NLY, DD, DD);
    prep_t_kernel<<<(NLY*DD*DFF + 255)/256, 256, 0, stream>>>(W1, W1t, NLY, DD, DFF);
    prep_t_kernel<<<(NLY*DFF*DD + 255)/256, 256, 0, stream>>>(W2, W2t, NLY, DFF, DD);
    prep_t_kernel<<<(DD*DD + 255)/256, 256, 0, stream>>>(sW1, sW1t, 1, DD, DD);
    prep_t_kernel<<<(DD*DD + 255)/256, 256, 0, stream>>>(sWn1, sWn1t, 1, DD, DD);
    prep_t_kernel<<<(DD*DD + 255)/256, 256, 0, stream>>>(sW2, sW2t, 1, DD, DD);
    prep_t_kernel<<<(DD*DD + 255)/256, 256, 0, stream>>>(sWn2, sWn2t, 1, DD, DD);
    prep_bias_kernel<<<(NLY*QS + 255)/256, 256, 0, stream>>>(bq, bk, bv, bqkvp);

    // ---- CSR build ----
    zero_int_kernel<<<NN / 256, 256, 0, stream>>>(counts, NN);
    count_edges_kernel<<<NE / 256, 256, 0, stream>>>(ei + NE, counts);
    scan_kernel<<<1, 256, 0, stream>>>(counts, offsets, cursor);
    fill_csr_kernel<<<NE / 256, 256, 0, stream>>>(ei, ei + NE, cursor, csr);

    // ---- SAGE ----
    agg_mean16_kernel<<<NN / 16, 256, 0, stream>>>(x, offsets, csr, agg0);
    gemm_f32b_kernel<1, true><<<dim3(DD / 64, NN / 64), 256, 0, stream>>>(
        x, sW0, agg0, sWn0, sb0, z0b, NN, DD, CIN);
    agg_mean_b_kernel<<<NN / 4, 256, 0, stream>>>(z0b, offsets, csr, a1b);
    mfma_gemm_kernel<1, true, false, true><<<dim3(DD / 128, NN / 128), 256, 0, stream>>>(
        z0b, sW1t, a1b, sWn1t, sb1, nullptr, z1b, NN, DD, DD);
    agg_mean_b_kernel<<<NN / 4, 256, 0, stream>>>(z1b, offsets, csr, a2b);
    mfma_gemm_kernel<0, true, true, false><<<dim3(DD / 128, NN / 128), 256, 0, stream>>>(
        z1b, sW2t, a2b, sWn2t, sb2, z2f, nullptr, NN, DD, DD);

    // ---- pack ----
    zero_f4_kernel<<<((size_t)NR * DD / 4) / 256, 256, 0, stream>>>((float4*)Hf, NR * DD / 4);
    zero_f4_kernel<<<((size_t)NR * DD / 8) / 256, 256, 0, stream>>>((float4*)Hb, NR * DD / 8);
    pack_kernel<<<NN / 4, 256, 0, stream>>>(z2f, batches, Hf, Hb);

    // ---- transformer ----
    for (int l = 0; l < NLY; ++l) {
        mfma_gemm_kernel<0, false, true, false><<<dim3(QS / 128, NR / 128), 256, 0, stream>>>(
            Hb, Wqkvt + (size_t)l * QS * DD, nullptr, nullptr,
            bqkvp + (size_t)l * QS, QKVf, nullptr, NR, QS, DD);
        attn_kernel<<<NG * NHD, 320, 0, stream>>>(QKVf, batches, Ob);
        mfma_gemm_kernel<0, false, true, false><<<dim3(DD / 128, NR / 128), 256, 0, stream>>>(
            Ob, Wot + (size_t)l * DD * DD, nullptr, nullptr,
            bo + (size_t)l * DD, Of, nullptr, NR, DD, DD);
        add_ln_kernel<<<NR / 4, 256, 0, stream>>>(
            Hf, Of, ln1g + (size_t)l * DD, ln1b + (size_t)l * DD, Hf, Hb);
        mfma_gemm_kernel<1, false, false, true><<<dim3(DFF / 128, NR / 128), 256, 0, stream>>>(
            Hb, W1t + (size_t)l * DFF * DD, nullptr, nullptr,
            b1 + (size_t)l * DFF, nullptr, F1b, NR, DFF, DD);
        mfma_gemm_kernel<0, false, true, false><<<dim3(DD / 128, NR / 128), 256, 0, stream>>>(
            F1b, W2t + (size_t)l * DD * DFF, nullptr, nullptr,
            b2 + (size_t)l * DD, F2f, nullptr, NR, DD, DFF);
        float* outp = (l == NLY - 1) ? (float*)d_out : Hf;
        add_ln_kernel<<<NR / 4, 256, 0, stream>>>(
            Hf, F2f, ln2g + (size_t)l * DD, ln2b + (size_t)l * DD, outp, Hb);
    }
}

// Round 3
// 1030.550 us; speedup vs baseline: 2.7195x; 1.3330x over previous
//
#include <hip/hip_runtime.h>
#include <hip/hip_bf16.h>
#include <math.h>

#define NN  16384      // nodes
#define NE  262144     // edges
#define NG  64         // graphs
#define CIN 16         // input colors
#define DD  256        // embedding
#define NHD 8          // heads
#define DHD 32         // head dim
#define DFF 1024       // ffn dim
#define NLY 4          // layers
#define LM  320        // L_max
#define NR  (LM*NG)    // padded rows = 20480
#define QS  768        // fused QKV row stride
#define ACH 32         // attention q-rows per block

typedef __attribute__((ext_vector_type(8))) short bf16x8;
typedef __attribute__((ext_vector_type(4))) float f32x4;
typedef __attribute__((ext_vector_type(8))) unsigned short u16x8;

__device__ __forceinline__ unsigned short f2bf(float f) {
    union { __hip_bfloat16 h; unsigned short u; } cv;
    cv.h = __float2bfloat16(f);
    return cv.u;
}
__device__ __forceinline__ float bf2f(unsigned short u) {
    return __uint_as_float((unsigned int)u << 16);
}

// ---------------------------------------------------------------- utilities
__global__ void zero_int_kernel(int* __restrict__ p, int n) {
    int i = blockIdx.x * 256 + threadIdx.x;
    if (i < n) p[i] = 0;
}
__global__ void zero_f4_kernel(float4* __restrict__ p, int n4) {
    int i = blockIdx.x * 256 + threadIdx.x;
    if (i < n4) p[i] = make_float4(0.f, 0.f, 0.f, 0.f);
}

// ---------------------------------------------------------------- weight prep (f32 -> bf16, transposed [N][K])
__global__ void prep_t_kernel(const float* __restrict__ in, unsigned short* __restrict__ out,
                              int L, int K, int N) {
    int i = blockIdx.x * 256 + threadIdx.x;
    if (i >= L * K * N) return;
    int k = i % K;
    int n = (i / K) % N;
    int l = i / (K * N);
    out[i] = f2bf(in[((size_t)l * K + k) * N + n]);
}

// QKV fused weight: scale folded into the Q block (s = (q*scale)·k)
__global__ void prep_qkv_kernel(const float* __restrict__ Wq, const float* __restrict__ Wk,
                                const float* __restrict__ Wv, unsigned short* __restrict__ out) {
    int i = blockIdx.x * 256 + threadIdx.x;   // [l][n(768)][k(256)]
    if (i >= NLY * QS * DD) return;
    int k = i & 255;
    int n = (i >> 8) % QS;
    int l = i / (QS * DD);
    const float* W = (n < 256) ? Wq : (n < 512 ? Wk : Wv);
    float w = W[((size_t)l * DD + k) * DD + (n & 255)];
    if (n < 256) w *= 0.17677669529663687f;   // 1/sqrt(32)
    out[i] = f2bf(w);
}

__global__ void prep_bias_kernel(const float* __restrict__ bq, const float* __restrict__ bk,
                                 const float* __restrict__ bv, float* __restrict__ out) {
    int i = blockIdx.x * 256 + threadIdx.x;   // [l][n(768)]
    if (i >= NLY * QS) return;
    int n = i % QS, l = i / QS;
    const float* b = (n < 256) ? bq : (n < 512 ? bk : bv);
    float v = b[l * DD + (n & 255)];
    if (n < 256) v *= 0.17677669529663687f;
    out[i] = v;
}

// ---------------------------------------------------------------- CSR build
__global__ void count_edges_kernel(const int* __restrict__ dst, int* __restrict__ counts) {
    int e = blockIdx.x * 256 + threadIdx.x;
    if (e < NE) atomicAdd(&counts[dst[e]], 1);
}

__global__ __launch_bounds__(256) void scan_kernel(const int* __restrict__ counts,
                                                   int* __restrict__ offsets,
                                                   int* __restrict__ cursor) {
    __shared__ int part[256];
    int t = threadIdx.x;
    int base = t * 64;
    int s = 0;
    for (int i = 0; i < 64; ++i) s += counts[base + i];
    part[t] = s;
    __syncthreads();
    for (int off = 1; off < 256; off <<= 1) {
        int val = (t >= off) ? part[t - off] : 0;
        __syncthreads();
        part[t] += val;
        __syncthreads();
    }
    int run = (t == 0) ? 0 : part[t - 1];
    for (int i = 0; i < 64; ++i) {
        offsets[base + i] = run;
        cursor[base + i]  = run;
        run += counts[base + i];
    }
    if (t == 255) offsets[NN] = run;
}

__global__ void fill_csr_kernel(const int* __restrict__ src, const int* __restrict__ dst,
                                int* __restrict__ cursor, int* __restrict__ csr) {
    int e = blockIdx.x * 256 + threadIdx.x;
    if (e < NE) {
        int p = atomicAdd(&cursor[dst[e]], 1);
        csr[p] = src[e];
    }
}

// ---------------------------------------------------------------- mean aggregation
__global__ __launch_bounds__(256) void agg_mean16_kernel(
    const float* __restrict__ h, const int* __restrict__ offsets,
    const int* __restrict__ csr, float* __restrict__ out)
{
    int node = blockIdx.x * 16 + (threadIdx.x >> 4);
    int d = threadIdx.x & 15;
    int beg = offsets[node], end = offsets[node + 1];
    float acc = 0.f;
    for (int e = beg; e < end; ++e) acc += h[(size_t)csr[e] * CIN + d];
    int dg = end - beg; if (dg < 1) dg = 1;
    out[(size_t)node * CIN + d] = acc * (1.f / (float)dg);
}

__global__ __launch_bounds__(256) void agg_mean_b_kernel(
    const unsigned short* __restrict__ h, const int* __restrict__ offsets,
    const int* __restrict__ csr, unsigned short* __restrict__ out)
{
    int node = blockIdx.x * 4 + (threadIdx.x >> 6);
    int lane = threadIdx.x & 63;
    int beg = offsets[node], end = offsets[node + 1];
    float a0 = 0.f, a1 = 0.f, a2 = 0.f, a3 = 0.f;
    for (int e = beg; e < end; ++e) {
        const ushort4 hv = *(const ushort4*)(h + (size_t)csr[e] * DD + lane * 4);
        a0 += bf2f(hv.x); a1 += bf2f(hv.y); a2 += bf2f(hv.z); a3 += bf2f(hv.w);
    }
    int dg = end - beg; if (dg < 1) dg = 1;
    float inv = 1.f / (float)dg;
    ushort4 ov;
    ov.x = f2bf(a0 * inv); ov.y = f2bf(a1 * inv);
    ov.z = f2bf(a2 * inv); ov.w = f2bf(a3 * inv);
    *(ushort4*)(out + (size_t)node * DD + lane * 4) = ov;
}

// ---------------------------------------------------------------- f32 tiled GEMM (SAGE layer0, K=16) -> bf16 out
template <int ACT, bool DUAL>
__global__ __launch_bounds__(256) void gemm_f32b_kernel(
    const float* __restrict__ A, const float* __restrict__ W,
    const float* __restrict__ A2, const float* __restrict__ W2,
    const float* __restrict__ bias, unsigned short* __restrict__ Cb,
    int M, int N, int K)
{
    __shared__ __align__(16) float As[16][64];
    __shared__ __align__(16) float Ws[16][64];
    const int t  = threadIdx.x;
    const int tx = t & 15, ty = t >> 4;
    const int m0 = blockIdx.y * 64, n0 = blockIdx.x * 64;
    const int arow = t >> 2, acol = (t & 3) * 4;
    const int wrow = t >> 4, wcol = (t & 15) * 4;
    float acc[4][4] = {};
    const int npass = DUAL ? 2 : 1;
    for (int pass = 0; pass < npass; ++pass) {
        const float* Ap = (DUAL && pass) ? A2 : A;
        const float* Wp = (DUAL && pass) ? W2 : W;
        for (int k0 = 0; k0 < K; k0 += 16) {
            __syncthreads();
            float4 av = *(const float4*)(Ap + (size_t)(m0 + arow) * K + k0 + acol);
            As[acol + 0][arow] = av.x;
            As[acol + 1][arow] = av.y;
            As[acol + 2][arow] = av.z;
            As[acol + 3][arow] = av.w;
            *(float4*)&Ws[wrow][wcol] = *(const float4*)(Wp + (size_t)(k0 + wrow) * N + n0 + wcol);
            __syncthreads();
            #pragma unroll
            for (int kk = 0; kk < 16; ++kk) {
                float4 a4 = *(const float4*)&As[kk][ty * 4];
                float4 b4 = *(const float4*)&Ws[kk][tx * 4];
                float aa[4] = {a4.x, a4.y, a4.z, a4.w};
                float bb[4] = {b4.x, b4.y, b4.z, b4.w};
                #pragma unroll
                for (int i = 0; i < 4; ++i)
                    #pragma unroll
                    for (int j = 0; j < 4; ++j)
                        acc[i][j] += aa[i] * bb[j];
            }
        }
    }
    float4 bv = *(const float4*)(bias + n0 + tx * 4);
    float bb4[4] = {bv.x, bv.y, bv.z, bv.w};
    #pragma unroll
    for (int i = 0; i < 4; ++i) {
        float c[4];
        #pragma unroll
        for (int j = 0; j < 4; ++j) {
            c[j] = acc[i][j] + bb4[j];
            if (ACT == 1) c[j] = fmaxf(c[j], 0.f);
        }
        ushort4 ov;
        ov.x = f2bf(c[0]); ov.y = f2bf(c[1]); ov.z = f2bf(c[2]); ov.w = f2bf(c[3]);
        *(ushort4*)(Cb + (size_t)(m0 + ty * 4 + i) * N + n0 + tx * 4) = ov;
    }
}

// ---------------------------------------------------------------- bf16 MFMA GEMM
// C[M,N] = act( A@W (+A2@W2) + bias ); A:[M,K] bf16 rm, Wt:[N,K] bf16 (pre-transposed).
template <int ACT, bool DUAL, bool OUTF32, bool OUTBF16>
__global__ __launch_bounds__(256) void mfma_gemm_kernel(
    const unsigned short* __restrict__ A,  const unsigned short* __restrict__ Wt,
    const unsigned short* __restrict__ A2, const unsigned short* __restrict__ Wt2,
    const float* __restrict__ bias, float* __restrict__ Cf,
    unsigned short* __restrict__ Cb, int M, int N, int K)
{
    __shared__ __align__(16) unsigned short As[128][40];
    __shared__ __align__(16) unsigned short Bs[128][40];
    const int t = threadIdx.x;
    const int wave = t >> 6, lane = t & 63;
    const int quad = lane >> 4, r16 = lane & 15;
    const int wr = (wave >> 1) * 64, wc = (wave & 1) * 64;
    const int m0 = blockIdx.y * 128, n0 = blockIdx.x * 128;
    const int srow = t >> 2, sq = (t & 3) * 8;

    f32x4 acc[4][4];
    #pragma unroll
    for (int i = 0; i < 4; ++i)
        #pragma unroll
        for (int j = 0; j < 4; ++j)
            acc[i][j] = (f32x4){0.f, 0.f, 0.f, 0.f};

    const int npass = DUAL ? 2 : 1;
    for (int pass = 0; pass < npass; ++pass) {
        const unsigned short* Ap = (DUAL && pass) ? A2 : A;
        const unsigned short* Wp = (DUAL && pass) ? Wt2 : Wt;
        for (int k0 = 0; k0 < K; k0 += 32) {
            __syncthreads();
            *(uint4*)&As[srow][sq]      = *(const uint4*)&Ap[(size_t)(m0 + srow) * K + k0 + sq];
            *(uint4*)&As[srow + 64][sq] = *(const uint4*)&Ap[(size_t)(m0 + srow + 64) * K + k0 + sq];
            *(uint4*)&Bs[srow][sq]      = *(const uint4*)&Wp[(size_t)(n0 + srow) * K + k0 + sq];
            *(uint4*)&Bs[srow + 64][sq] = *(const uint4*)&Wp[(size_t)(n0 + srow + 64) * K + k0 + sq];
            __syncthreads();
            bf16x8 af[4], bfr[4];
            #pragma unroll
            for (int i = 0; i < 4; ++i)
                af[i] = *(const bf16x8*)&As[wr + i * 16 + r16][quad * 8];
            #pragma unroll
            for (int j = 0; j < 4; ++j)
                bfr[j] = *(const bf16x8*)&Bs[wc + j * 16 + r16][quad * 8];
            #pragma unroll
            for (int i = 0; i < 4; ++i)
                #pragma unroll
                for (int j = 0; j < 4; ++j)
                    acc[i][j] = __builtin_amdgcn_mfma_f32_16x16x32_bf16(
                        af[i], bfr[j], acc[i][j], 0, 0, 0);
        }
    }

    float bcol[4];
    #pragma unroll
    for (int j = 0; j < 4; ++j) bcol[j] = bias[n0 + wc + j * 16 + r16];
    #pragma unroll
    for (int i = 0; i < 4; ++i) {
        const int rowb = m0 + wr + i * 16 + quad * 4;
        #pragma unroll
        for (int rr = 0; rr < 4; ++rr) {
            const size_t rb = (size_t)(rowb + rr) * N;
            #pragma unroll
            for (int j = 0; j < 4; ++j) {
                float v = acc[i][j][rr] + bcol[j];
                if (ACT == 1) v = fmaxf(v, 0.f);
                const int col = n0 + wc + j * 16 + r16;
                if (OUTF32) Cf[rb + col] = v;
                if (OUTBF16) Cb[rb + col] = f2bf(v);
            }
        }
    }
}

// ---------------------------------------------------------------- pack to padded [L,B,D] (f32 + bf16)
__global__ __launch_bounds__(256) void pack_kernel(
    const float* __restrict__ z, const int* __restrict__ batches,
    float* __restrict__ Hf, unsigned short* __restrict__ Hb)
{
    int node = blockIdx.x * 4 + (threadIdx.x >> 6);
    int lane = threadIdx.x & 63;
    int lo = 0, hi = NG;
    while (lo < hi) {
        int mid = (lo + hi + 1) >> 1;
        if (batches[mid] <= node) lo = mid; else hi = mid - 1;
    }
    int pos = node - batches[lo];
    size_t base = ((size_t)pos * NG + lo) * DD + lane * 4;
    float4 zv = *(const float4*)(z + (size_t)node * DD + lane * 4);
    *(float4*)(Hf + base) = zv;
    ushort4 hb;
    hb.x = f2bf(zv.x); hb.y = f2bf(zv.y); hb.z = f2bf(zv.z); hb.w = f2bf(zv.w);
    *(ushort4*)(Hb + base) = hb;
}

// ---------------------------------------------------------------- MFMA flash attention
// qkv: [LM*NG rows][768] bf16 (Q pre-scaled). Block = (graph, 32-row chunk), 8 waves = 8 heads.
// Per 32-key tile: S = Q K^T (4 MFMAs), online softmax (C-layout), P->LDS->A-layout, PV (4 MFMAs).
__global__ __launch_bounds__(512) void attn_mfma_kernel(
    const unsigned short* __restrict__ qkv, const int* __restrict__ batches,
    unsigned short* __restrict__ o)
{
    // V transposed tile: element V[k][d] at VtS[(k>>3)*2056 + d*8 + (k&7)]
    // quad stride 2056 (pad +8) so b128 reads spread 8 bank-classes.
    __shared__ __align__(16) unsigned short VtS[4 * 2056];
    __shared__ __align__(16) unsigned short PsS[NHD][ACH][40];   // P per wave, pad 40

    const int b = blockIdx.x & 63;
    const int chunk = blockIdx.x >> 6;
    const int q0 = chunk * ACH;
    const int len = batches[b + 1] - batches[b];
    const int tid = threadIdx.x;
    const int wave = tid >> 6;       // head
    const int lane = tid & 63;
    const int quad = lane >> 4, r16 = lane & 15;

    // Q fragments (A-layout: m=r16, k=quad*8+j) straight from global
    bf16x8 qf[2];
    #pragma unroll
    for (int i = 0; i < 2; ++i)
        qf[i] = *(const bf16x8*)(qkv + ((size_t)(q0 + i * 16 + r16) * NG + b) * QS
                                 + wave * 32 + quad * 8);

    f32x4 oacc[2][2];
    #pragma unroll
    for (int i = 0; i < 2; ++i)
        #pragma unroll
        for (int nt = 0; nt < 2; ++nt)
            oacc[i][nt] = (f32x4){0.f, 0.f, 0.f, 0.f};
    float mst[2][4], lst[2][4];
    #pragma unroll
    for (int i = 0; i < 2; ++i)
        #pragma unroll
        for (int r = 0; r < 4; ++r) { mst[i][r] = -1e30f; lst[i][r] = 0.f; }

    const int vm = tid & 31;             // key for V staging
    const int vd = (tid >> 5) * 16;      // dim base

    for (int t0 = 0; t0 < len; t0 += 32) {
        // ---- stage V transposed
        {
            int row = t0 + vm; if (row > LM - 1) row = LM - 1;
            const unsigned short* vp = qkv + ((size_t)row * NG + b) * QS + 512 + vd;
            uint4 v0 = *(const uint4*)vp;
            uint4 v1 = *(const uint4*)(vp + 8);
            unsigned short* dst = &VtS[(vm >> 3) * 2056 + (vm & 7)];
            const unsigned short* e0 = (const unsigned short*)&v0;
            #pragma unroll
            for (int j = 0; j < 8; ++j) dst[(vd + j) * 8] = e0[j];
            const unsigned short* e1 = (const unsigned short*)&v1;
            #pragma unroll
            for (int j = 0; j < 8; ++j) dst[(vd + 8 + j) * 8] = e1[j];
        }
        // ---- K fragments from global (B-layout: n=key=r16, k=dim=quad*8+j)
        bf16x8 kf[2];
        #pragma unroll
        for (int kt = 0; kt < 2; ++kt) {
            int kr = t0 + kt * 16 + r16; if (kr > LM - 1) kr = LM - 1;
            kf[kt] = *(const bf16x8*)(qkv + ((size_t)kr * NG + b) * QS + 256
                                      + wave * 32 + quad * 8);
        }
        __syncthreads();
        // ---- S = Q K^T
        f32x4 sf[2][2];
        #pragma unroll
        for (int i = 0; i < 2; ++i)
            #pragma unroll
            for (int kt = 0; kt < 2; ++kt)
                sf[i][kt] = (f32x4){0.f, 0.f, 0.f, 0.f};
        #pragma unroll
        for (int i = 0; i < 2; ++i)
            #pragma unroll
            for (int kt = 0; kt < 2; ++kt)
                sf[i][kt] = __builtin_amdgcn_mfma_f32_16x16x32_bf16(
                    qf[i], kf[kt], sf[i][kt], 0, 0, 0);
        // ---- mask invalid keys (col = kt*16 + r16)
        #pragma unroll
        for (int kt = 0; kt < 2; ++kt) {
            if (t0 + kt * 16 + r16 >= len) {
                #pragma unroll
                for (int r = 0; r < 4; ++r) { sf[0][kt][r] = -1e30f; sf[1][kt][r] = -1e30f; }
            }
        }
        // ---- online softmax (row = quad*4 + r + 16*i, cols across quad's 16 lanes)
        float al[2][4];
        #pragma unroll
        for (int i = 0; i < 2; ++i) {
            #pragma unroll
            for (int r = 0; r < 4; ++r) {
                float mt = fmaxf(sf[i][0][r], sf[i][1][r]);
                mt = fmaxf(mt, __shfl_xor(mt, 1, 64));
                mt = fmaxf(mt, __shfl_xor(mt, 2, 64));
                mt = fmaxf(mt, __shfl_xor(mt, 4, 64));
                mt = fmaxf(mt, __shfl_xor(mt, 8, 64));
                float mnew = fmaxf(mst[i][r], mt);
                float alpha = __expf(mst[i][r] - mnew);
                mst[i][r] = mnew;
                al[i][r] = alpha;
                float p0 = __expf(sf[i][0][r] - mnew);
                float p1 = __expf(sf[i][1][r] - mnew);
                int row = i * 16 + quad * 4 + r;
                PsS[wave][row][r16]      = f2bf(p0);
                PsS[wave][row][16 + r16] = f2bf(p1);
                float ps = p0 + p1;
                ps += __shfl_xor(ps, 1, 64);
                ps += __shfl_xor(ps, 2, 64);
                ps += __shfl_xor(ps, 4, 64);
                ps += __shfl_xor(ps, 8, 64);
                lst[i][r] = lst[i][r] * alpha + ps;
            }
        }
        #pragma unroll
        for (int i = 0; i < 2; ++i)
            #pragma unroll
            for (int nt = 0; nt < 2; ++nt)
                #pragma unroll
                for (int r = 0; r < 4; ++r)
                    oacc[i][nt][r] *= al[i][r];
        // wave-local LDS RAW fence (Ps written above, read below by same wave)
        __asm__ volatile("s_waitcnt lgkmcnt(0)" ::: "memory");
        // ---- PV
        bf16x8 pf[2], vf[2];
        #pragma unroll
        for (int i = 0; i < 2; ++i)
            pf[i] = *(const bf16x8*)&PsS[wave][i * 16 + r16][quad * 8];
        #pragma unroll
        for (int nt = 0; nt < 2; ++nt)
            vf[nt] = *(const bf16x8*)&VtS[quad * 2056 + (wave * 32 + nt * 16 + r16) * 8];
        #pragma unroll
        for (int i = 0; i < 2; ++i)
            #pragma unroll
            for (int nt = 0; nt < 2; ++nt)
                oacc[i][nt] = __builtin_amdgcn_mfma_f32_16x16x32_bf16(
                    pf[i], vf[nt], oacc[i][nt], 0, 0, 0);
        __syncthreads();   // all waves done with VtS before next stage
    }
    // ---- epilogue: O / l, bf16 out
    #pragma unroll
    for (int i = 0; i < 2; ++i) {
        #pragma unroll
        for (int r = 0; r < 4; ++r) {
            float inv = 1.f / lst[i][r];
            int qrow = q0 + i * 16 + quad * 4 + r;
            size_t base = ((size_t)qrow * NG + b) * DD + wave * 32;
            #pragma unroll
            for (int nt = 0; nt < 2; ++nt)
                o[base + nt * 16 + r16] = f2bf(oacc[i][nt][r] * inv);
        }
    }
}

// ---------------------------------------------------------------- residual + LayerNorm (f32 + bf16 out)
__global__ __launch_bounds__(256) void add_ln_kernel(
    const float* __restrict__ x, const float* __restrict__ r,
    const float* __restrict__ g, const float* __restrict__ bb,
    float* __restrict__ outf, unsigned short* __restrict__ outb)
{
    int row  = blockIdx.x * 4 + (threadIdx.x >> 6);
    int lane = threadIdx.x & 63;
    size_t base = (size_t)row * DD + lane * 4;
    float4 xv = *(const float4*)(x + base);
    float4 rv = *(const float4*)(r + base);
    float t0 = xv.x + rv.x, t1 = xv.y + rv.y, t2 = xv.z + rv.z, t3 = xv.w + rv.w;
    float s1 = t0 + t1 + t2 + t3;
    float s2 = t0*t0 + t1*t1 + t2*t2 + t3*t3;
    #pragma unroll
    for (int off = 32; off > 0; off >>= 1) {
        s1 += __shfl_xor(s1, off, 64);
        s2 += __shfl_xor(s2, off, 64);
    }
    float mean = s1 * (1.f / 256.f);
    float var  = s2 * (1.f / 256.f) - mean * mean;
    float rs = rsqrtf(var + 1e-5f);
    float4 gv = *(const float4*)(g + lane * 4);
    float4 bv = *(const float4*)(bb + lane * 4);
    float4 ov;
    ov.x = (t0 - mean) * rs * gv.x + bv.x;
    ov.y = (t1 - mean) * rs * gv.y + bv.y;
    ov.z = (t2 - mean) * rs * gv.z + bv.z;
    ov.w = (t3 - mean) * rs * gv.w + bv.w;
    *(float4*)(outf + base) = ov;
    ushort4 ob;
    ob.x = f2bf(ov.x); ob.y = f2bf(ov.y); ob.z = f2bf(ov.z); ob.w = f2bf(ov.w);
    *(ushort4*)(outb + base) = ob;
}

// ---------------------------------------------------------------- launcher
extern "C" void kernel_launch(void* const* d_in, const int* in_sizes, int n_in,
                              void* d_out, int out_size, void* d_ws, size_t ws_size,
                              hipStream_t stream) {
    const float* x       = (const float*)d_in[0];
    const int*   ei      = (const int*)d_in[1];
    const int*   batches = (const int*)d_in[2];
    const float* sW0  = (const float*)d_in[4];
    const float* sWn0 = (const float*)d_in[5];
    const float* sb0  = (const float*)d_in[6];
    const float* sW1  = (const float*)d_in[7];
    const float* sWn1 = (const float*)d_in[8];
    const float* sb1  = (const float*)d_in[9];
    const float* sW2  = (const float*)d_in[10];
    const float* sWn2 = (const float*)d_in[11];
    const float* sb2  = (const float*)d_in[12];
    const float* Wq   = (const float*)d_in[13];
    const float* Wk   = (const float*)d_in[14];
    const float* Wv   = (const float*)d_in[15];
    const float* bq   = (const float*)d_in[16];
    const float* bk   = (const float*)d_in[17];
    const float* bv   = (const float*)d_in[18];
    const float* Wo   = (const float*)d_in[19];
    const float* bo   = (const float*)d_in[20];
    const float* ln1g = (const float*)d_in[21];
    const float* ln1b = (const float*)d_in[22];
    const float* ln2g = (const float*)d_in[23];
    const float* ln2b = (const float*)d_in[24];
    const float* W1   = (const float*)d_in[25];
    const float* b1   = (const float*)d_in[26];
    const float* W2   = (const float*)d_in[27];
    const float* b2   = (const float*)d_in[28];

    char* p = (char*)d_ws;
    auto alloc = [&](size_t bytes) {
        char* r = p;
        p += (bytes + 255) & ~(size_t)255;
        return r;
    };
    int*   counts  = (int*)alloc((size_t)NN * 4);
    int*   offsets = (int*)alloc((size_t)(NN + 1) * 4);
    int*   cursor  = (int*)alloc((size_t)NN * 4);
    int*   csr     = (int*)alloc((size_t)NE * 4);
    float* agg0    = (float*)alloc((size_t)NN * CIN * 4);
    unsigned short* z0b = (unsigned short*)alloc((size_t)NN * DD * 2);
    unsigned short* a1b = (unsigned short*)alloc((size_t)NN * DD * 2);
    unsigned short* z1b = (unsigned short*)alloc((size_t)NN * DD * 2);
    unsigned short* a2b = (unsigned short*)alloc((size_t)NN * DD * 2);
    float* z2f     = (float*)alloc((size_t)NN * DD * 4);
    float* Hf      = (float*)alloc((size_t)NR * DD * 4);
    unsigned short* Hb = (unsigned short*)alloc((size_t)NR * DD * 2);
    unsigned short* Ob = (unsigned short*)alloc((size_t)NR * DD * 2);
    float* R       = (float*)alloc((size_t)NR * QS * 4);   // QKVb/Of/F1b/F2f alias region
    unsigned short* QKVb = (unsigned short*)R;             // [NR,768] bf16 = 31.5 MB
    float* Of      = R;                                    // [NR,256] f32 (after attn)
    unsigned short* F1b = (unsigned short*)R;              // [NR,1024] bf16 = 40 MB
    float* F2f     = (float*)((char*)R + (size_t)NR * DFF * 2);
    // weights (bf16, transposed [N][K])
    unsigned short* Wqkvt = (unsigned short*)alloc((size_t)NLY * QS * DD * 2);
    unsigned short* Wot   = (unsigned short*)alloc((size_t)NLY * DD * DD * 2);
    unsigned short* W1t   = (unsigned short*)alloc((size_t)NLY * DFF * DD * 2);
    unsigned short* W2t   = (unsigned short*)alloc((size_t)NLY * DD * DFF * 2);
    unsigned short* sW1t  = (unsigned short*)alloc((size_t)DD * DD * 2);
    unsigned short* sWn1t = (unsigned short*)alloc((size_t)DD * DD * 2);
    unsigned short* sW2t  = (unsigned short*)alloc((size_t)DD * DD * 2);
    unsigned short* sWn2t = (unsigned short*)alloc((size_t)DD * DD * 2);
    float* bqkvp   = (float*)alloc((size_t)NLY * QS * 4);

    // ---- weight prep ----
    prep_qkv_kernel<<<(NLY*QS*DD + 255)/256, 256, 0, stream>>>(Wq, Wk, Wv, Wqkvt);
    prep_t_kernel<<<(NLY*DD*DD + 255)/256, 256, 0, stream>>>(Wo, Wot, NLY, DD, DD);
    prep_t_kernel<<<(NLY*DD*DFF + 255)/256, 256, 0, stream>>>(W1, W1t, NLY, DD, DFF);
    prep_t_kernel<<<(NLY*DFF*DD + 255)/256, 256, 0, stream>>>(W2, W2t, NLY, DFF, DD);
    prep_t_kernel<<<(DD*DD + 255)/256, 256, 0, stream>>>(sW1, sW1t, 1, DD, DD);
    prep_t_kernel<<<(DD*DD + 255)/256, 256, 0, stream>>>(sWn1, sWn1t, 1, DD, DD);
    prep_t_kernel<<<(DD*DD + 255)/256, 256, 0, stream>>>(sW2, sW2t, 1, DD, DD);
    prep_t_kernel<<<(DD*DD + 255)/256, 256, 0, stream>>>(sWn2, sWn2t, 1, DD, DD);
    prep_bias_kernel<<<(NLY*QS + 255)/256, 256, 0, stream>>>(bq, bk, bv, bqkvp);

    // ---- CSR build ----
    zero_int_kernel<<<NN / 256, 256, 0, stream>>>(counts, NN);
    count_edges_kernel<<<NE / 256, 256, 0, stream>>>(ei + NE, counts);
    scan_kernel<<<1, 256, 0, stream>>>(counts, offsets, cursor);
    fill_csr_kernel<<<NE / 256, 256, 0, stream>>>(ei, ei + NE, cursor, csr);

    // ---- SAGE ----
    agg_mean16_kernel<<<NN / 16, 256, 0, stream>>>(x, offsets, csr, agg0);
    gemm_f32b_kernel<1, true><<<dim3(DD / 64, NN / 64), 256, 0, stream>>>(
        x, sW0, agg0, sWn0, sb0, z0b, NN, DD, CIN);
    agg_mean_b_kernel<<<NN / 4, 256, 0, stream>>>(z0b, offsets, csr, a1b);
    mfma_gemm_kernel<1, true, false, true><<<dim3(DD / 128, NN / 128), 256, 0, stream>>>(
        z0b, sW1t, a1b, sWn1t, sb1, nullptr, z1b, NN, DD, DD);
    agg_mean_b_kernel<<<NN / 4, 256, 0, stream>>>(z1b, offsets, csr, a2b);
    mfma_gemm_kernel<0, true, true, false><<<dim3(DD / 128, NN / 128), 256, 0, stream>>>(
        z1b, sW2t, a2b, sWn2t, sb2, z2f, nullptr, NN, DD, DD);

    // ---- pack ----
    zero_f4_kernel<<<((size_t)NR * DD / 4) / 256, 256, 0, stream>>>((float4*)Hf, NR * DD / 4);
    zero_f4_kernel<<<((size_t)NR * DD / 8) / 256, 256, 0, stream>>>((float4*)Hb, NR * DD / 8);
    pack_kernel<<<NN / 4, 256, 0, stream>>>(z2f, batches, Hf, Hb);

    // ---- transformer ----
    for (int l = 0; l < NLY; ++l) {
        mfma_gemm_kernel<0, false, false, true><<<dim3(QS / 128, NR / 128), 256, 0, stream>>>(
            Hb, Wqkvt + (size_t)l * QS * DD, nullptr, nullptr,
            bqkvp + (size_t)l * QS, nullptr, QKVb, NR, QS, DD);
        attn_mfma_kernel<<<NG * (LM / ACH), 512, 0, stream>>>(QKVb, batches, Ob);
        mfma_gemm_kernel<0, false, true, false><<<dim3(DD / 128, NR / 128), 256, 0, stream>>>(
            Ob, Wot + (size_t)l * DD * DD, nullptr, nullptr,
            bo + (size_t)l * DD, Of, nullptr, NR, DD, DD);
        add_ln_kernel<<<NR / 4, 256, 0, stream>>>(
            Hf, Of, ln1g + (size_t)l * DD, ln1b + (size_t)l * DD, Hf, Hb);
        mfma_gemm_kernel<1, false, false, true><<<dim3(DFF / 128, NR / 128), 256, 0, stream>>>(
            Hb, W1t + (size_t)l * DFF * DD, nullptr, nullptr,
            b1 + (size_t)l * DFF, nullptr, F1b, NR, DFF, DD);
        mfma_gemm_kernel<0, false, true, false><<<dim3(DD / 128, NR / 128), 256, 0, stream>>>(
            F1b, W2t + (size_t)l * DD * DFF, nullptr, nullptr,
            b2 + (size_t)l * DD, F2f, nullptr, NR, DD, DFF);
        float* outp = (l == NLY - 1) ? (float*)d_out : Hf;
        add_ln_kernel<<<NR / 4, 256, 0, stream>>>(
            Hf, F2f, ln2g + (size_t)l * DD, ln2b + (size_t)l * DD, outp, Hb);
    }
}

// Round 4
// 920.236 us; speedup vs baseline: 3.0455x; 1.1199x over previous
//
#include <hip/hip_runtime.h>
#include <hip/hip_bf16.h>
#include <math.h>

#define NN  16384      // nodes
#define NE  262144     // edges
#define NG  64         // graphs
#define CIN 16         // input colors
#define DD  256        // embedding
#define NHD 8          // heads
#define DHD 32         // head dim
#define DFF 1024       // ffn dim
#define NLY 4          // layers
#define LM  320        // L_max
#define NR  (LM*NG)    // padded rows = 20480
#define QS  768        // fused QKV row stride
#define ACH 32         // attention q-rows per block

typedef __attribute__((ext_vector_type(8))) short bf16x8;
typedef __attribute__((ext_vector_type(4))) float f32x4;

__device__ __forceinline__ unsigned short f2bf(float f) {
    union { __hip_bfloat16 h; unsigned short u; } cv;
    cv.h = __float2bfloat16(f);
    return cv.u;
}
__device__ __forceinline__ float bf2f(unsigned short u) {
    return __uint_as_float((unsigned int)u << 16);
}
// async global->LDS 16B: dest = wave-uniform lds base + lane*16
__device__ __forceinline__ void gl_lds16(const unsigned short* g, unsigned short* l) {
    __builtin_amdgcn_global_load_lds(
        (const __attribute__((address_space(1))) unsigned int*)g,
        (__attribute__((address_space(3))) unsigned int*)l, 16, 0, 0);
}

// ---------------------------------------------------------------- utilities
__global__ void zero_int_kernel(int* __restrict__ p, int n) {
    int i = blockIdx.x * 256 + threadIdx.x;
    if (i < n) p[i] = 0;
}
__global__ void zero_f4_kernel(float4* __restrict__ p, int n4) {
    int i = blockIdx.x * 256 + threadIdx.x;
    if (i < n4) p[i] = make_float4(0.f, 0.f, 0.f, 0.f);
}

// ---------------------------------------------------------------- weight prep (f32 -> bf16, transposed [N][K])
__global__ void prep_t_kernel(const float* __restrict__ in, unsigned short* __restrict__ out,
                              int L, int K, int N) {
    int i = blockIdx.x * 256 + threadIdx.x;
    if (i >= L * K * N) return;
    int k = i % K;
    int n = (i / K) % N;
    int l = i / (K * N);
    out[i] = f2bf(in[((size_t)l * K + k) * N + n]);
}

// QKV fused weight: softmax scale folded into the Q block
__global__ void prep_qkv_kernel(const float* __restrict__ Wq, const float* __restrict__ Wk,
                                const float* __restrict__ Wv, unsigned short* __restrict__ out) {
    int i = blockIdx.x * 256 + threadIdx.x;   // [l][n(768)][k(256)]
    if (i >= NLY * QS * DD) return;
    int k = i & 255;
    int n = (i >> 8) % QS;
    int l = i / (QS * DD);
    const float* W = (n < 256) ? Wq : (n < 512 ? Wk : Wv);
    float w = W[((size_t)l * DD + k) * DD + (n & 255)];
    if (n < 256) w *= 0.17677669529663687f;   // 1/sqrt(32)
    out[i] = f2bf(w);
}

__global__ void prep_bias_kernel(const float* __restrict__ bq, const float* __restrict__ bk,
                                 const float* __restrict__ bv, float* __restrict__ out) {
    int i = blockIdx.x * 256 + threadIdx.x;   // [l][n(768)]
    if (i >= NLY * QS) return;
    int n = i % QS, l = i / QS;
    const float* b = (n < 256) ? bq : (n < 512 ? bv : bv);
    b = (n < 256) ? bq : (n < 512 ? bk : bv);
    float v = b[l * DD + (n & 255)];
    if (n < 256) v *= 0.17677669529663687f;
    out[i] = v;
}

// ---------------------------------------------------------------- CSR build
__global__ void count_edges_kernel(const int* __restrict__ dst, int* __restrict__ counts) {
    int e = blockIdx.x * 256 + threadIdx.x;
    if (e < NE) atomicAdd(&counts[dst[e]], 1);
}

__global__ __launch_bounds__(256) void scan_kernel(const int* __restrict__ counts,
                                                   int* __restrict__ offsets,
                                                   int* __restrict__ cursor) {
    __shared__ int part[256];
    int t = threadIdx.x;
    int base = t * 64;
    int s = 0;
    for (int i = 0; i < 64; ++i) s += counts[base + i];
    part[t] = s;
    __syncthreads();
    for (int off = 1; off < 256; off <<= 1) {
        int val = (t >= off) ? part[t - off] : 0;
        __syncthreads();
        part[t] += val;
        __syncthreads();
    }
    int run = (t == 0) ? 0 : part[t - 1];
    for (int i = 0; i < 64; ++i) {
        offsets[base + i] = run;
        cursor[base + i]  = run;
        run += counts[base + i];
    }
    if (t == 255) offsets[NN] = run;
}

__global__ void fill_csr_kernel(const int* __restrict__ src, const int* __restrict__ dst,
                                int* __restrict__ cursor, int* __restrict__ csr) {
    int e = blockIdx.x * 256 + threadIdx.x;
    if (e < NE) {
        int p = atomicAdd(&cursor[dst[e]], 1);
        csr[p] = src[e];
    }
}

// ---------------------------------------------------------------- mean aggregation
__global__ __launch_bounds__(256) void agg_mean16_kernel(
    const float* __restrict__ h, const int* __restrict__ offsets,
    const int* __restrict__ csr, float* __restrict__ out)
{
    int node = blockIdx.x * 16 + (threadIdx.x >> 4);
    int d = threadIdx.x & 15;
    int beg = offsets[node], end = offsets[node + 1];
    float acc = 0.f;
    for (int e = beg; e < end; ++e) acc += h[(size_t)csr[e] * CIN + d];
    int dg = end - beg; if (dg < 1) dg = 1;
    out[(size_t)node * CIN + d] = acc * (1.f / (float)dg);
}

__global__ __launch_bounds__(256) void agg_mean_b_kernel(
    const unsigned short* __restrict__ h, const int* __restrict__ offsets,
    const int* __restrict__ csr, unsigned short* __restrict__ out)
{
    int node = blockIdx.x * 4 + (threadIdx.x >> 6);
    int lane = threadIdx.x & 63;
    int beg = offsets[node], end = offsets[node + 1];
    float a0 = 0.f, a1 = 0.f, a2 = 0.f, a3 = 0.f;
    for (int e = beg; e < end; ++e) {
        const ushort4 hv = *(const ushort4*)(h + (size_t)csr[e] * DD + lane * 4);
        a0 += bf2f(hv.x); a1 += bf2f(hv.y); a2 += bf2f(hv.z); a3 += bf2f(hv.w);
    }
    int dg = end - beg; if (dg < 1) dg = 1;
    float inv = 1.f / (float)dg;
    ushort4 ov;
    ov.x = f2bf(a0 * inv); ov.y = f2bf(a1 * inv);
    ov.z = f2bf(a2 * inv); ov.w = f2bf(a3 * inv);
    *(ushort4*)(out + (size_t)node * DD + lane * 4) = ov;
}

// ---------------------------------------------------------------- f32 tiled GEMM (SAGE layer0, K=16) -> bf16 out
template <int ACT, bool DUAL>
__global__ __launch_bounds__(256) void gemm_f32b_kernel(
    const float* __restrict__ A, const float* __restrict__ W,
    const float* __restrict__ A2, const float* __restrict__ W2,
    const float* __restrict__ bias, unsigned short* __restrict__ Cb,
    int M, int N, int K)
{
    __shared__ __align__(16) float As[16][64];
    __shared__ __align__(16) float Ws[16][64];
    const int t  = threadIdx.x;
    const int tx = t & 15, ty = t >> 4;
    const int m0 = blockIdx.y * 64, n0 = blockIdx.x * 64;
    const int arow = t >> 2, acol = (t & 3) * 4;
    const int wrow = t >> 4, wcol = (t & 15) * 4;
    float acc[4][4] = {};
    const int npass = DUAL ? 2 : 1;
    for (int pass = 0; pass < npass; ++pass) {
        const float* Ap = (DUAL && pass) ? A2 : A;
        const float* Wp = (DUAL && pass) ? W2 : W;
        for (int k0 = 0; k0 < K; k0 += 16) {
            __syncthreads();
            float4 av = *(const float4*)(Ap + (size_t)(m0 + arow) * K + k0 + acol);
            As[acol + 0][arow] = av.x;
            As[acol + 1][arow] = av.y;
            As[acol + 2][arow] = av.z;
            As[acol + 3][arow] = av.w;
            *(float4*)&Ws[wrow][wcol] = *(const float4*)(Wp + (size_t)(k0 + wrow) * N + n0 + wcol);
            __syncthreads();
            #pragma unroll
            for (int kk = 0; kk < 16; ++kk) {
                float4 a4 = *(const float4*)&As[kk][ty * 4];
                float4 b4 = *(const float4*)&Ws[kk][tx * 4];
                float aa[4] = {a4.x, a4.y, a4.z, a4.w};
                float bb[4] = {b4.x, b4.y, b4.z, b4.w};
                #pragma unroll
                for (int i = 0; i < 4; ++i)
                    #pragma unroll
                    for (int j = 0; j < 4; ++j)
                        acc[i][j] += aa[i] * bb[j];
            }
        }
    }
    float4 bv = *(const float4*)(bias + n0 + tx * 4);
    float bb4[4] = {bv.x, bv.y, bv.z, bv.w};
    #pragma unroll
    for (int i = 0; i < 4; ++i) {
        float c[4];
        #pragma unroll
        for (int j = 0; j < 4; ++j) {
            c[j] = acc[i][j] + bb4[j];
            if (ACT == 1) c[j] = fmaxf(c[j], 0.f);
        }
        ushort4 ov;
        ov.x = f2bf(c[0]); ov.y = f2bf(c[1]); ov.z = f2bf(c[2]); ov.w = f2bf(c[3]);
        *(ushort4*)(Cb + (size_t)(m0 + ty * 4 + i) * N + n0 + tx * 4) = ov;
    }
}

// ---------------------------------------------------------------- bf16 MFMA GEMM (m97 recipe)
// C[M,N] = act( A@W (+A2@W2) + bias ); A:[M,K] bf16 rm, Wt:[N,K] bf16 (pre-transposed).
// 128x128 tile, BK=32, global_load_lds width=16, unpadded 64B LDS rows.
template <int ACT, bool DUAL, bool OUTF32, bool OUTBF16>
__global__ __launch_bounds__(256) void mfma_gemm_kernel(
    const unsigned short* __restrict__ A,  const unsigned short* __restrict__ Wt,
    const unsigned short* __restrict__ A2, const unsigned short* __restrict__ Wt2,
    const float* __restrict__ bias, float* __restrict__ Cf,
    unsigned short* __restrict__ Cb, int M, int N, int K)
{
    __shared__ __align__(16) unsigned short As[128 * 32];
    __shared__ __align__(16) unsigned short Bs[128 * 32];
    const int t = threadIdx.x;
    const int wave = t >> 6, lane = t & 63;
    const int quad = lane >> 4, r16 = lane & 15;
    const int wr = (wave >> 1) * 64, wc = (wave & 1) * 64;
    const int m0 = blockIdx.y * 128, n0 = blockIdx.x * 128;
    const int srow = t >> 2, sq = (t & 3) * 8;   // staging map: byte off = t*16

    unsigned short* la = As + wave * 512;        // wave-uniform LDS dests
    unsigned short* lb = Bs + wave * 512;

    f32x4 acc[4][4];
    #pragma unroll
    for (int i = 0; i < 4; ++i)
        #pragma unroll
        for (int j = 0; j < 4; ++j)
            acc[i][j] = (f32x4){0.f, 0.f, 0.f, 0.f};

    const int npass = DUAL ? 2 : 1;
    for (int pass = 0; pass < npass; ++pass) {
        const unsigned short* Ap = (DUAL && pass) ? A2 : A;
        const unsigned short* Wp = (DUAL && pass) ? Wt2 : Wt;
        for (int k0 = 0; k0 < K; k0 += 32) {
            __syncthreads();
            gl_lds16(&Ap[(size_t)(m0 + srow) * K + k0 + sq],       la);
            gl_lds16(&Ap[(size_t)(m0 + 64 + srow) * K + k0 + sq],  la + 2048);
            gl_lds16(&Wp[(size_t)(n0 + srow) * K + k0 + sq],       lb);
            gl_lds16(&Wp[(size_t)(n0 + 64 + srow) * K + k0 + sq],  lb + 2048);
            __syncthreads();
            bf16x8 af[4], bfr[4];
            #pragma unroll
            for (int i = 0; i < 4; ++i)
                af[i] = *(const bf16x8*)&As[(wr + i * 16 + r16) * 32 + quad * 8];
            #pragma unroll
            for (int j = 0; j < 4; ++j)
                bfr[j] = *(const bf16x8*)&Bs[(wc + j * 16 + r16) * 32 + quad * 8];
            #pragma unroll
            for (int i = 0; i < 4; ++i)
                #pragma unroll
                for (int j = 0; j < 4; ++j)
                    acc[i][j] = __builtin_amdgcn_mfma_f32_16x16x32_bf16(
                        af[i], bfr[j], acc[i][j], 0, 0, 0);
        }
    }

    float bcol[4];
    #pragma unroll
    for (int j = 0; j < 4; ++j) bcol[j] = bias[n0 + wc + j * 16 + r16];
    #pragma unroll
    for (int i = 0; i < 4; ++i) {
        const int rowb = m0 + wr + i * 16 + quad * 4;
        #pragma unroll
        for (int rr = 0; rr < 4; ++rr) {
            const size_t rb = (size_t)(rowb + rr) * N;
            #pragma unroll
            for (int j = 0; j < 4; ++j) {
                float v = acc[i][j][rr] + bcol[j];
                if (ACT == 1) v = fmaxf(v, 0.f);
                const int col = n0 + wc + j * 16 + r16;
                if (OUTF32) Cf[rb + col] = v;
                if (OUTBF16) Cb[rb + col] = f2bf(v);
            }
        }
    }
}

// ---------------------------------------------------------------- pack to graph-major padded [g][pos][D]
__global__ __launch_bounds__(256) void pack_kernel(
    const float* __restrict__ z, const int* __restrict__ batches,
    float* __restrict__ Hf, unsigned short* __restrict__ Hb)
{
    int node = blockIdx.x * 4 + (threadIdx.x >> 6);
    int lane = threadIdx.x & 63;
    int lo = 0, hi = NG;
    while (lo < hi) {
        int mid = (lo + hi + 1) >> 1;
        if (batches[mid] <= node) lo = mid; else hi = mid - 1;
    }
    int pos = node - batches[lo];
    size_t base = ((size_t)lo * LM + pos) * DD + lane * 4;
    float4 zv = *(const float4*)(z + (size_t)node * DD + lane * 4);
    *(float4*)(Hf + base) = zv;
    ushort4 hb;
    hb.x = f2bf(zv.x); hb.y = f2bf(zv.y); hb.z = f2bf(zv.z); hb.w = f2bf(zv.w);
    *(ushort4*)(Hb + base) = hb;
}

// ---------------------------------------------------------------- MFMA flash attention, no-max softmax
// qkv graph-major: row (g*LM+pos), 768 cols (Q|K|V), Q pre-scaled. Block=(graph, 32 q rows),
// 8 waves = 8 heads. Unnormalized p=exp(s); row-sum l via MFMA with ones-B (no shuffles).
__global__ __launch_bounds__(512) void attn_mfma_kernel(
    const unsigned short* __restrict__ qkv, const int* __restrict__ batches,
    unsigned short* __restrict__ o)
{
    // V^T tile: V[k][d] at VtS[(k>>3)*2056 + d*8 + (k&7)]
    __shared__ __align__(16) unsigned short VtS[4 * 2056];
    __shared__ __align__(16) unsigned short PsS[NHD][ACH][40];

    const int b = blockIdx.x & 63;
    const int chunk = blockIdx.x >> 6;
    const int q0 = chunk * ACH;
    const int len = batches[b + 1] - batches[b];
    const int tid = threadIdx.x;
    const int wave = tid >> 6;       // head
    const int lane = tid & 63;
    const int quad = lane >> 4, r16 = lane & 15;
    const size_t gbase = (size_t)b * LM;

    bf16x8 qf[2];
    #pragma unroll
    for (int i = 0; i < 2; ++i)
        qf[i] = *(const bf16x8*)(qkv + (gbase + q0 + i * 16 + r16) * QS
                                 + wave * 32 + quad * 8);
    bf16x8 onesf;
    #pragma unroll
    for (int j = 0; j < 8; ++j) onesf[j] = (short)0x3F80;   // bf16 1.0

    f32x4 oacc[2][2], lacc[2];
    #pragma unroll
    for (int i = 0; i < 2; ++i) {
        lacc[i] = (f32x4){0.f, 0.f, 0.f, 0.f};
        #pragma unroll
        for (int nt = 0; nt < 2; ++nt)
            oacc[i][nt] = (f32x4){0.f, 0.f, 0.f, 0.f};
    }

    const int vm = tid & 31;             // key index for V staging
    const int vd = (tid >> 5) * 16;      // dim base

    for (int t0 = 0; t0 < len; t0 += 32) {
        // ---- stage V^T
        {
            const unsigned short* vp = qkv + (gbase + t0 + vm) * QS + 512 + vd;
            uint4 v0 = *(const uint4*)vp;
            uint4 v1 = *(const uint4*)(vp + 8);
            unsigned short* dst = &VtS[(vm >> 3) * 2056 + (vm & 7)];
            const unsigned short* e0 = (const unsigned short*)&v0;
            #pragma unroll
            for (int j = 0; j < 8; ++j) dst[(vd + j) * 8] = e0[j];
            const unsigned short* e1 = (const unsigned short*)&v1;
            #pragma unroll
            for (int j = 0; j < 8; ++j) dst[(vd + 8 + j) * 8] = e1[j];
        }
        // ---- K fragments (B-layout: n=key=r16, k=dim=quad*8+j)
        bf16x8 kf[2];
        #pragma unroll
        for (int kt = 0; kt < 2; ++kt)
            kf[kt] = *(const bf16x8*)(qkv + (gbase + t0 + kt * 16 + r16) * QS + 256
                                      + wave * 32 + quad * 8);
        __syncthreads();
        // ---- S = Q K^T
        f32x4 sf[2][2];
        #pragma unroll
        for (int i = 0; i < 2; ++i)
            #pragma unroll
            for (int kt = 0; kt < 2; ++kt)
                sf[i][kt] = (f32x4){0.f, 0.f, 0.f, 0.f};
        #pragma unroll
        for (int i = 0; i < 2; ++i)
            #pragma unroll
            for (int kt = 0; kt < 2; ++kt)
                sf[i][kt] = __builtin_amdgcn_mfma_f32_16x16x32_bf16(
                    qf[i], kf[kt], sf[i][kt], 0, 0, 0);
        // ---- p = exp(s), masked; write P tile (A-layout via LDS)
        const bool v0ok = (t0 + r16) < len;
        const bool v1ok = (t0 + 16 + r16) < len;
        #pragma unroll
        for (int i = 0; i < 2; ++i) {
            #pragma unroll
            for (int r = 0; r < 4; ++r) {
                float p0 = v0ok ? __expf(sf[i][0][r]) : 0.f;
                float p1 = v1ok ? __expf(sf[i][1][r]) : 0.f;
                int row = i * 16 + quad * 4 + r;
                PsS[wave][row][r16]      = f2bf(p0);
                PsS[wave][row][16 + r16] = f2bf(p1);
            }
        }
        // wave-local LDS RAW fence (P written above, read below by same wave)
        __asm__ volatile("s_waitcnt lgkmcnt(0)" ::: "memory");
        // ---- O += P V ; l += P * ones
        bf16x8 pf[2], vf[2];
        #pragma unroll
        for (int i = 0; i < 2; ++i)
            pf[i] = *(const bf16x8*)&PsS[wave][i * 16 + r16][quad * 8];
        #pragma unroll
        for (int nt = 0; nt < 2; ++nt)
            vf[nt] = *(const bf16x8*)&VtS[quad * 2056 + (wave * 32 + nt * 16 + r16) * 8];
        #pragma unroll
        for (int i = 0; i < 2; ++i) {
            #pragma unroll
            for (int nt = 0; nt < 2; ++nt)
                oacc[i][nt] = __builtin_amdgcn_mfma_f32_16x16x32_bf16(
                    pf[i], vf[nt], oacc[i][nt], 0, 0, 0);
            lacc[i] = __builtin_amdgcn_mfma_f32_16x16x32_bf16(
                pf[i], onesf, lacc[i], 0, 0, 0);
        }
        __syncthreads();   // all waves done with VtS before restage
    }
    // ---- epilogue: O / l
    #pragma unroll
    for (int i = 0; i < 2; ++i) {
        #pragma unroll
        for (int r = 0; r < 4; ++r) {
            float inv = 1.f / lacc[i][r];
            size_t base = (gbase + q0 + i * 16 + quad * 4 + r) * DD + wave * 32;
            #pragma unroll
            for (int nt = 0; nt < 2; ++nt)
                o[base + nt * 16 + r16] = f2bf(oacc[i][nt][r] * inv);
        }
    }
}

// ---------------------------------------------------------------- residual + LayerNorm (f32 + bf16 out)
// PERM: write outf at seq-first index (pos*NG+g) for the final layer's d_out.
template <bool PERM>
__global__ __launch_bounds__(256) void add_ln_kernel(
    const float* __restrict__ x, const float* __restrict__ r,
    const float* __restrict__ g, const float* __restrict__ bb,
    float* __restrict__ outf, unsigned short* __restrict__ outb)
{
    int row  = blockIdx.x * 4 + (threadIdx.x >> 6);
    int lane = threadIdx.x & 63;
    size_t base = (size_t)row * DD + lane * 4;
    float4 xv = *(const float4*)(x + base);
    float4 rv = *(const float4*)(r + base);
    float t0 = xv.x + rv.x, t1 = xv.y + rv.y, t2 = xv.z + rv.z, t3 = xv.w + rv.w;
    float s1 = t0 + t1 + t2 + t3;
    float s2 = t0*t0 + t1*t1 + t2*t2 + t3*t3;
    #pragma unroll
    for (int off = 32; off > 0; off >>= 1) {
        s1 += __shfl_xor(s1, off, 64);
        s2 += __shfl_xor(s2, off, 64);
    }
    float mean = s1 * (1.f / 256.f);
    float var  = s2 * (1.f / 256.f) - mean * mean;
    float rs = rsqrtf(var + 1e-5f);
    float4 gv = *(const float4*)(g + lane * 4);
    float4 bv = *(const float4*)(bb + lane * 4);
    float4 ov;
    ov.x = (t0 - mean) * rs * gv.x + bv.x;
    ov.y = (t1 - mean) * rs * gv.y + bv.y;
    ov.z = (t2 - mean) * rs * gv.z + bv.z;
    ov.w = (t3 - mean) * rs * gv.w + bv.w;
    size_t obase = base;
    if (PERM) {
        int gg = row / LM, pos = row - gg * LM;
        obase = ((size_t)pos * NG + gg) * DD + lane * 4;
    }
    *(float4*)(outf + obase) = ov;
    ushort4 ob;
    ob.x = f2bf(ov.x); ob.y = f2bf(ov.y); ob.z = f2bf(ov.z); ob.w = f2bf(ov.w);
    *(ushort4*)(outb + base) = ob;
}

// ---------------------------------------------------------------- launcher
extern "C" void kernel_launch(void* const* d_in, const int* in_sizes, int n_in,
                              void* d_out, int out_size, void* d_ws, size_t ws_size,
                              hipStream_t stream) {
    const float* x       = (const float*)d_in[0];
    const int*   ei      = (const int*)d_in[1];
    const int*   batches = (const int*)d_in[2];
    const float* sW0  = (const float*)d_in[4];
    const float* sWn0 = (const float*)d_in[5];
    const float* sb0  = (const float*)d_in[6];
    const float* sW1  = (const float*)d_in[7];
    const float* sWn1 = (const float*)d_in[8];
    const float* sb1  = (const float*)d_in[9];
    const float* sW2  = (const float*)d_in[10];
    const float* sWn2 = (const float*)d_in[11];
    const float* sb2  = (const float*)d_in[12];
    const float* Wq   = (const float*)d_in[13];
    const float* Wk   = (const float*)d_in[14];
    const float* Wv   = (const float*)d_in[15];
    const float* bq   = (const float*)d_in[16];
    const float* bk   = (const float*)d_in[17];
    const float* bv   = (const float*)d_in[18];
    const float* Wo   = (const float*)d_in[19];
    const float* bo   = (const float*)d_in[20];
    const float* ln1g = (const float*)d_in[21];
    const float* ln1b = (const float*)d_in[22];
    const float* ln2g = (const float*)d_in[23];
    const float* ln2b = (const float*)d_in[24];
    const float* W1   = (const float*)d_in[25];
    const float* b1   = (const float*)d_in[26];
    const float* W2   = (const float*)d_in[27];
    const float* b2   = (const float*)d_in[28];

    char* p = (char*)d_ws;
    auto alloc = [&](size_t bytes) {
        char* r = p;
        p += (bytes + 255) & ~(size_t)255;
        return r;
    };
    int*   counts  = (int*)alloc((size_t)NN * 4);
    int*   offsets = (int*)alloc((size_t)(NN + 1) * 4);
    int*   cursor  = (int*)alloc((size_t)NN * 4);
    int*   csr     = (int*)alloc((size_t)NE * 4);
    float* agg0    = (float*)alloc((size_t)NN * CIN * 4);
    unsigned short* z0b = (unsigned short*)alloc((size_t)NN * DD * 2);
    unsigned short* a1b = (unsigned short*)alloc((size_t)NN * DD * 2);
    unsigned short* z1b = (unsigned short*)alloc((size_t)NN * DD * 2);
    unsigned short* a2b = (unsigned short*)alloc((size_t)NN * DD * 2);
    float* z2f     = (float*)alloc((size_t)NN * DD * 4);
    float* Hf      = (float*)alloc((size_t)NR * DD * 4);
    unsigned short* Hb = (unsigned short*)alloc((size_t)NR * DD * 2);
    unsigned short* Ob = (unsigned short*)alloc((size_t)NR * DD * 2);
    float* R       = (float*)alloc((size_t)NR * QS * 4);   // QKVb/Of/F1b/F2f alias region
    unsigned short* QKVb = (unsigned short*)R;             // [NR,768] bf16
    float* Of      = R;                                    // [NR,256] f32
    unsigned short* F1b = (unsigned short*)R;              // [NR,1024] bf16
    float* F2f     = (float*)((char*)R + (size_t)NR * DFF * 2);
    // weights (bf16, transposed [N][K])
    unsigned short* Wqkvt = (unsigned short*)alloc((size_t)NLY * QS * DD * 2);
    unsigned short* Wot   = (unsigned short*)alloc((size_t)NLY * DD * DD * 2);
    unsigned short* W1t   = (unsigned short*)alloc((size_t)NLY * DFF * DD * 2);
    unsigned short* W2t   = (unsigned short*)alloc((size_t)NLY * DD * DFF * 2);
    unsigned short* sW1t  = (unsigned short*)alloc((size_t)DD * DD * 2);
    unsigned short* sWn1t = (unsigned short*)alloc((size_t)DD * DD * 2);
    unsigned short* sW2t  = (unsigned short*)alloc((size_t)DD * DD * 2);
    unsigned short* sWn2t = (unsigned short*)alloc((size_t)DD * DD * 2);
    float* bqkvp   = (float*)alloc((size_t)NLY * QS * 4);

    // ---- weight prep ----
    prep_qkv_kernel<<<(NLY*QS*DD + 255)/256, 256, 0, stream>>>(Wq, Wk, Wv, Wqkvt);
    prep_t_kernel<<<(NLY*DD*DD + 255)/256, 256, 0, stream>>>(Wo, Wot, NLY, DD, DD);
    prep_t_kernel<<<(NLY*DD*DFF + 255)/256, 256, 0, stream>>>(W1, W1t, NLY, DD, DFF);
    prep_t_kernel<<<(NLY*DFF*DD + 255)/256, 256, 0, stream>>>(W2, W2t, NLY, DFF, DD);
    prep_t_kernel<<<(DD*DD + 255)/256, 256, 0, stream>>>(sW1, sW1t, 1, DD, DD);
    prep_t_kernel<<<(DD*DD + 255)/256, 256, 0, stream>>>(sWn1, sWn1t, 1, DD, DD);
    prep_t_kernel<<<(DD*DD + 255)/256, 256, 0, stream>>>(sW2, sW2t, 1, DD, DD);
    prep_t_kernel<<<(DD*DD + 255)/256, 256, 0, stream>>>(sWn2, sWn2t, 1, DD, DD);
    prep_bias_kernel<<<(NLY*QS + 255)/256, 256, 0, stream>>>(bq, bk, bv, bqkvp);

    // ---- CSR build ----
    zero_int_kernel<<<NN / 256, 256, 0, stream>>>(counts, NN);
    count_edges_kernel<<<NE / 256, 256, 0, stream>>>(ei + NE, counts);
    scan_kernel<<<1, 256, 0, stream>>>(counts, offsets, cursor);
    fill_csr_kernel<<<NE / 256, 256, 0, stream>>>(ei, ei + NE, cursor, csr);

    // ---- SAGE ----
    agg_mean16_kernel<<<NN / 16, 256, 0, stream>>>(x, offsets, csr, agg0);
    gemm_f32b_kernel<1, true><<<dim3(DD / 64, NN / 64), 256, 0, stream>>>(
        x, sW0, agg0, sWn0, sb0, z0b, NN, DD, CIN);
    agg_mean_b_kernel<<<NN / 4, 256, 0, stream>>>(z0b, offsets, csr, a1b);
    mfma_gemm_kernel<1, true, false, true><<<dim3(DD / 128, NN / 128), 256, 0, stream>>>(
        z0b, sW1t, a1b, sWn1t, sb1, nullptr, z1b, NN, DD, DD);
    agg_mean_b_kernel<<<NN / 4, 256, 0, stream>>>(z1b, offsets, csr, a2b);
    mfma_gemm_kernel<0, true, true, false><<<dim3(DD / 128, NN / 128), 256, 0, stream>>>(
        z1b, sW2t, a2b, sWn2t, sb2, z2f, nullptr, NN, DD, DD);

    // ---- pack (graph-major) ----
    zero_f4_kernel<<<((size_t)NR * DD / 4) / 256, 256, 0, stream>>>((float4*)Hf, NR * DD / 4);
    zero_f4_kernel<<<((size_t)NR * DD / 8) / 256, 256, 0, stream>>>((float4*)Hb, NR * DD / 8);
    pack_kernel<<<NN / 4, 256, 0, stream>>>(z2f, batches, Hf, Hb);

    // ---- transformer ----
    for (int l = 0; l < NLY; ++l) {
        mfma_gemm_kernel<0, false, false, true><<<dim3(QS / 128, NR / 128), 256, 0, stream>>>(
            Hb, Wqkvt + (size_t)l * QS * DD, nullptr, nullptr,
            bqkvp + (size_t)l * QS, nullptr, QKVb, NR, QS, DD);
        attn_mfma_kernel<<<NG * (LM / ACH), 512, 0, stream>>>(QKVb, batches, Ob);
        mfma_gemm_kernel<0, false, true, false><<<dim3(DD / 128, NR / 128), 256, 0, stream>>>(
            Ob, Wot + (size_t)l * DD * DD, nullptr, nullptr,
            bo + (size_t)l * DD, Of, nullptr, NR, DD, DD);
        add_ln_kernel<false><<<NR / 4, 256, 0, stream>>>(
            Hf, Of, ln1g + (size_t)l * DD, ln1b + (size_t)l * DD, Hf, Hb);
        mfma_gemm_kernel<1, false, false, true><<<dim3(DFF / 128, NR / 128), 256, 0, stream>>>(
            Hb, W1t + (size_t)l * DFF * DD, nullptr, nullptr,
            b1 + (size_t)l * DFF, nullptr, F1b, NR, DFF, DD);
        mfma_gemm_kernel<0, false, true, false><<<dim3(DD / 128, NR / 128), 256, 0, stream>>>(
            F1b, W2t + (size_t)l * DD * DFF, nullptr, nullptr,
            b2 + (size_t)l * DD, F2f, nullptr, NR, DD, DFF);
        if (l == NLY - 1)
            add_ln_kernel<true><<<NR / 4, 256, 0, stream>>>(
                Hf, F2f, ln2g + (size_t)l * DD, ln2b + (size_t)l * DD, (float*)d_out, Hb);
        else
            add_ln_kernel<false><<<NR / 4, 256, 0, stream>>>(
                Hf, F2f, ln2g + (size_t)l * DD, ln2b + (size_t)l * DD, Hf, Hb);
    }
}